// Round 1
// baseline (2251.729 us; speedup 1.0000x reference)
//
#include <hip/hip_runtime.h>

#define EPS 1e-8f
#define NU_MOL 1.5e-5f

// ws layout (bytes):
//   [0,   64): double scalars d[0..7]: mse, div, mom, prod, diss, wallcnt, bc, wall
//   [64, 576): double smooth_slots[64]
//   [576, 580): int flag (1 = edge_index is int64, 0 = int32)
//   [1024, 1024+7*N*4): 7 node accumulator arrays (float):
//       a_cnt, a_div, a_pgx, a_pgy, a_lu, a_lv, a_str

__global__ void detect_idx_dtype(const void* eidx, int N, int* flag) {
    const long long* ll = (const long long*)eidx;
    int is64 = 1;
    for (int i = 0; i < 16; ++i) {
        long long v = ll[i];
        if (v < 0 || v >= (long long)N) { is64 = 0; break; }
    }
    *flag = is64;
}

__global__ __launch_bounds__(256) void edge_kernel(
    const void* __restrict__ eidx, const float2* __restrict__ eattr,
    const float4* __restrict__ pred, int E, int N, const int* __restrict__ flag,
    float* __restrict__ a_cnt, float* __restrict__ a_div,
    float* __restrict__ a_pgx, float* __restrict__ a_pgy,
    float* __restrict__ a_lu, float* __restrict__ a_lv,
    float* __restrict__ a_str, double* __restrict__ smooth_slots)
{
    const int is64 = *flag;
    const long long* ll = (const long long*)eidx;
    const int* ii = (const int*)eidx;
    double smooth = 0.0;
    const int stride = gridDim.x * blockDim.x;
    for (int e = blockIdx.x * blockDim.x + threadIdx.x; e < E; e += stride) {
        int row, col;
        if (is64) {
            row = (int)ll[e];
            col = (int)ll[(long long)E + e];
        } else {
            row = ii[e];
            col = ii[E + e];
        }
        // safety clamp (prevents fault if dtype detection is somehow wrong)
        row = min(max(row, 0), N - 1);
        col = min(max(col, 0), N - 1);

        float2 dxy = eattr[e];
        float4 pr = pred[row];
        float4 pc = pred[col];
        float du = pc.x - pr.x;
        float dv = pc.y - pr.y;
        float dp = pc.z - pr.z;
        float dn = pc.w - pr.w;

        float rx  = 1.0f / (dxy.x + EPS);
        float ry  = 1.0f / (dxy.y + EPS);
        float rx2 = 1.0f / (dxy.x * dxy.x + EPS);
        float ry2 = 1.0f / (dxy.y * dxy.y + EPS);

        float du_dx = du * rx, du_dy = du * ry;
        float dv_dx = dv * rx, dv_dy = dv * ry;

        atomicAdd(&a_cnt[row], 1.0f);
        atomicAdd(&a_div[row], du_dx + dv_dy);   // seg(du/dx)+seg(dv/dy) fused
        atomicAdd(&a_pgx[row], dp * rx);
        atomicAdd(&a_pgy[row], dp * ry);
        atomicAdd(&a_lu[row], du * rx2);
        atomicAdd(&a_lv[row], dv * ry2);
        float shear = du_dy + dv_dx;
        atomicAdd(&a_str[row], 2.0f * (du_dx * du_dx + dv_dy * dv_dy) + shear * shear);

        smooth += (double)(du * du + dv * dv + dp * dp + dn * dn);
    }

    // block-reduce smooth, one atomic per block into 64 slots
    for (int off = 32; off > 0; off >>= 1)
        smooth += __shfl_down(smooth, off);
    __shared__ double sm[4];
    int lane = threadIdx.x & 63, wv = threadIdx.x >> 6;
    if (lane == 0) sm[wv] = smooth;
    __syncthreads();
    if (threadIdx.x == 0) {
        double t = sm[0] + sm[1] + sm[2] + sm[3];
        atomicAdd(&smooth_slots[blockIdx.x & 63], t);
    }
}

__global__ __launch_bounds__(256) void node_kernel(
    const float4* __restrict__ pred, const float4* __restrict__ tgt,
    const unsigned char* __restrict__ wall, int N,
    const float* __restrict__ a_cnt, const float* __restrict__ a_div,
    const float* __restrict__ a_pgx, const float* __restrict__ a_pgy,
    const float* __restrict__ a_lu, const float* __restrict__ a_lv,
    const float* __restrict__ a_str, double* __restrict__ d)
{
    int i = blockIdx.x * blockDim.x + threadIdx.x;
    double v0 = 0, v1 = 0, v2 = 0, v3 = 0, v4 = 0, v5 = 0, v6 = 0, v7 = 0;
    if (i < N) {
        float4 p = pred[i];
        float4 t = tgt[i];
        float inv = 1.0f / fmaxf(a_cnt[i], 1.0f);
        float div = a_div[i] * inv;
        float pgx = a_pgx[i] * inv, pgy = a_pgy[i] * inv;
        float lu = a_lu[i] * inv, lv = a_lv[i] * inv;
        float nu_eff = NU_MOL + p.w;
        float mx = pgx + nu_eff * lu;
        float my = pgy + nu_eff * lv;
        float sn = a_str[i] * inv;
        float prod = p.w * sn;
        float m = wall[i] ? 1.0f : 0.0f;
        float e0 = p.x - t.x, e1 = p.y - t.y, e2 = p.z - t.z, e3 = p.w - t.w;
        float uv = p.x * p.x + p.y * p.y;
        v0 = (double)(e0 * e0 + e1 * e1 + e2 * e2 + e3 * e3);
        v1 = (double)div * (double)div;
        v2 = (double)mx * (double)mx + (double)my * (double)my;
        v3 = (double)prod * (double)prod;
        v4 = (double)p.w * (double)p.w;
        v5 = (double)m;
        v6 = (double)(m * uv);
        v7 = (double)(m * (uv + p.w * p.w));
    }
    for (int off = 32; off > 0; off >>= 1) {
        v0 += __shfl_down(v0, off); v1 += __shfl_down(v1, off);
        v2 += __shfl_down(v2, off); v3 += __shfl_down(v3, off);
        v4 += __shfl_down(v4, off); v5 += __shfl_down(v5, off);
        v6 += __shfl_down(v6, off); v7 += __shfl_down(v7, off);
    }
    __shared__ double sm[4][8];
    int lane = threadIdx.x & 63, wv = threadIdx.x >> 6;
    if (lane == 0) {
        sm[wv][0] = v0; sm[wv][1] = v1; sm[wv][2] = v2; sm[wv][3] = v3;
        sm[wv][4] = v4; sm[wv][5] = v5; sm[wv][6] = v6; sm[wv][7] = v7;
    }
    __syncthreads();
    if (threadIdx.x < 8) {
        int q = threadIdx.x;
        double t = sm[0][q] + sm[1][q] + sm[2][q] + sm[3][q];
        atomicAdd(&d[q], t);
    }
}

__global__ void finalize_kernel(const double* __restrict__ d,
                                const double* __restrict__ smooth_slots,
                                int N, int E, float* __restrict__ out)
{
    double smooth = 0.0;
    for (int i = 0; i < 64; ++i) smooth += smooth_slots[i];
    double dN = (double)N;
    double n_wall = d[5] > 1.0 ? d[5] : 1.0;
    // cont_w = mom_w = 0.1 (curriculum constant: INIT == TGT)
    double total = 1.0  * d[0] / (4.0 * dN)      // mse
                 + 0.1  * d[1] / dN              // div
                 + 0.1  * d[2] / dN              // momentum
                 + 0.05 * d[3] / dN              // turb production
                 + 0.05 * d[4] / dN              // turb dissipation
                 + 0.05 * d[6] / n_wall          // bc
                 + 0.01 * smooth / (4.0 * (double)E)  // smooth
                 + 0.02 * d[7] / n_wall;         // wall
    out[0] = (float)total;
}

extern "C" void kernel_launch(void* const* d_in, const int* in_sizes, int n_in,
                              void* d_out, int out_size, void* d_ws, size_t ws_size,
                              hipStream_t stream) {
    const float4* pred = (const float4*)d_in[0];
    const float4* tgt  = (const float4*)d_in[1];
    const float2* eattr = (const float2*)d_in[2];
    const void* eidx = d_in[3];
    const unsigned char* wall = (const unsigned char*)d_in[4];
    int N = in_sizes[0] / 4;
    int E = in_sizes[2] / 2;

    char* ws = (char*)d_ws;
    double* d = (double*)ws;                 // 8 scalars
    double* smooth_slots = d + 8;            // 64 slots
    int* flag = (int*)(ws + 576);
    float* arrays = (float*)(ws + 1024);
    float* a_cnt = arrays + (size_t)0 * N;
    float* a_div = arrays + (size_t)1 * N;
    float* a_pgx = arrays + (size_t)2 * N;
    float* a_pgy = arrays + (size_t)3 * N;
    float* a_lu  = arrays + (size_t)4 * N;
    float* a_lv  = arrays + (size_t)5 * N;
    float* a_str = arrays + (size_t)6 * N;

    size_t zbytes = 1024 + (size_t)7 * N * sizeof(float);
    hipMemsetAsync(d_ws, 0, zbytes, stream);

    detect_idx_dtype<<<1, 1, 0, stream>>>(eidx, N, flag);

    edge_kernel<<<4096, 256, 0, stream>>>(eidx, eattr, pred, E, N, flag,
                                          a_cnt, a_div, a_pgx, a_pgy,
                                          a_lu, a_lv, a_str, smooth_slots);

    node_kernel<<<(N + 255) / 256, 256, 0, stream>>>(pred, tgt, wall, N,
                                                     a_cnt, a_div, a_pgx, a_pgy,
                                                     a_lu, a_lv, a_str, d);

    finalize_kernel<<<1, 1, 0, stream>>>(d, smooth_slots, N, E, (float*)d_out);
}

// Round 2
// 752.589 us; speedup vs baseline: 2.9920x; 2.9920x over previous
//
#include <hip/hip_runtime.h>

#define EPS 1e-8f
#define NU_MOL 1.5e-5f
#define NPB 128            // nodes per bucket
#define MAXNB 832          // max buckets supported by LDS arrays (N <= 106496)
#define NBLK 1024          // edge-chunk blocks for count/scatter

// ===================== common =====================

__global__ void detect_idx_dtype(const void* eidx, int N, int* flag) {
    const long long* ll = (const long long*)eidx;
    int is64 = 1;
    for (int i = 0; i < 16; ++i) {
        long long v = ll[i];
        if (v < 0 || v >= (long long)N) { is64 = 0; break; }
    }
    *flag = is64;
}

__global__ void finalize_kernel(const double* __restrict__ d,
                                const double* __restrict__ smooth_slots,
                                int N, int E, float* __restrict__ out)
{
    double smooth = 0.0;
    for (int i = 0; i < 64; ++i) smooth += smooth_slots[i];
    double dN = (double)N;
    double n_wall = d[5] > 1.0 ? d[5] : 1.0;
    double total = 1.0  * d[0] / (4.0 * dN)
                 + 0.1  * d[1] / dN
                 + 0.1  * d[2] / dN
                 + 0.05 * d[3] / dN
                 + 0.05 * d[4] / dN
                 + 0.05 * d[6] / n_wall
                 + 0.01 * smooth / (4.0 * (double)E)
                 + 0.02 * d[7] / n_wall;
    out[0] = (float)total;
}

// ===================== fast path: bucket binning =====================

// Pass 1: per-(bucket, block) edge counts via LDS histogram. No global atomics.
__global__ __launch_bounds__(256) void count_kernel(
    const void* __restrict__ eidx, int E, int N, int NB,
    const int* __restrict__ flag, unsigned* __restrict__ counts /* [NB][NBLK] */)
{
    __shared__ unsigned hist[MAXNB];
    for (int i = threadIdx.x; i < NB; i += 256) hist[i] = 0u;
    __syncthreads();
    const int is64 = *flag;
    const long long* ll = (const long long*)eidx;
    const int* ii = (const int*)eidx;
    int chunk = (E + NBLK - 1) / NBLK;
    int s = blockIdx.x * chunk;
    int eend = min(E, s + chunk);
    for (int e = s + (int)threadIdx.x; e < eend; e += 256) {
        int r = is64 ? (int)ll[e] : ii[e];
        r = min(max(r, 0), N - 1);
        atomicAdd(&hist[r >> 7], 1u);          // LDS atomic
    }
    __syncthreads();
    for (int b = threadIdx.x; b < NB; b += 256)
        counts[(size_t)b * NBLK + blockIdx.x] = hist[b];
}

// Pass 2a: per-bucket exclusive scan over the NBLK block-counts (in place).
__global__ __launch_bounds__(256) void scan_rows(
    unsigned* __restrict__ counts, unsigned* __restrict__ totals)
{
    unsigned* rowp = counts + (size_t)blockIdx.x * NBLK;
    int t = threadIdx.x;
    uint4 v = ((const uint4*)rowp)[t];
    unsigned s = v.x + v.y + v.z + v.w;
    __shared__ unsigned sc[256];
    sc[t] = s; __syncthreads();
    for (int off = 1; off < 256; off <<= 1) {
        unsigned x = (t >= off) ? sc[t - off] : 0u;
        __syncthreads();
        sc[t] += x;
        __syncthreads();
    }
    unsigned ex = sc[t] - s;
    uint4 o;
    o.x = ex; ex += v.x;
    o.y = ex; ex += v.y;
    o.z = ex; ex += v.z;
    o.w = ex;
    ((uint4*)rowp)[t] = o;
    if (t == 255) totals[blockIdx.x] = sc[255];
}

// Pass 2b: exclusive scan of bucket totals -> base[NB+1].
__global__ __launch_bounds__(256) void scan_totals(
    const unsigned* __restrict__ totals, unsigned* __restrict__ base, int NB)
{
    int t = threadIdx.x;
    unsigned v[4]; unsigned s = 0;
    #pragma unroll
    for (int j = 0; j < 4; ++j) {
        int i = t * 4 + j;
        v[j] = (i < NB) ? totals[i] : 0u;
        s += v[j];
    }
    __shared__ unsigned sc[256];
    sc[t] = s; __syncthreads();
    for (int off = 1; off < 256; off <<= 1) {
        unsigned x = (t >= off) ? sc[t - off] : 0u;
        __syncthreads();
        sc[t] += x;
        __syncthreads();
    }
    unsigned ex = sc[t] - s;
    #pragma unroll
    for (int j = 0; j < 4; ++j) {
        int i = t * 4 + j;
        if (i < NB) base[i] = ex;
        ex += v[j];
    }
    if (t == 255) base[NB] = sc[255];
}

// Pass 3: compute per-edge quantities, scatter payload into bucket-sorted order
// using LDS cursors (ds_add_rtn). Also accumulates smooth loss.
__global__ __launch_bounds__(256) void scatter_kernel(
    const void* __restrict__ eidx, const float2* __restrict__ eattr,
    const float4* __restrict__ pred, int E, int N, int NB,
    const int* __restrict__ flag,
    const unsigned* __restrict__ localoff /* counts after scan */,
    const unsigned* __restrict__ base,
    float4* __restrict__ vals, unsigned* __restrict__ rloc,
    double* __restrict__ smooth_slots)
{
    __shared__ unsigned cur[MAXNB];
    for (int b = threadIdx.x; b < NB; b += 256)
        cur[b] = base[b] + localoff[(size_t)b * NBLK + blockIdx.x];
    __syncthreads();

    const int is64 = *flag;
    const long long* ll = (const long long*)eidx;
    const int* ii = (const int*)eidx;
    int chunk = (E + NBLK - 1) / NBLK;
    int s = blockIdx.x * chunk;
    int eend = min(E, s + chunk);
    double smooth = 0.0;
    for (int e = s + (int)threadIdx.x; e < eend; e += 256) {
        int r, c;
        if (is64) { r = (int)ll[e]; c = (int)ll[(long long)E + e]; }
        else      { r = ii[e];      c = ii[E + e]; }
        r = min(max(r, 0), N - 1);
        c = min(max(c, 0), N - 1);
        float2 dxy = eattr[e];
        float4 pr = pred[r];
        float4 pc = pred[c];
        float du = pc.x - pr.x, dv = pc.y - pr.y;
        float dp = pc.z - pr.z, dn = pc.w - pr.w;
        float rx  = 1.0f / (dxy.x + EPS);
        float ry  = 1.0f / (dxy.y + EPS);
        float rx2 = 1.0f / (dxy.x * dxy.x + EPS);
        float ry2 = 1.0f / (dxy.y * dxy.y + EPS);
        float du_dx = du * rx, du_dy = du * ry;
        float dv_dx = dv * rx, dv_dy = dv * ry;
        float nu_eff = NU_MOL + pr.w;          // segment-constant: fuse pgrad+nu*lap
        float div_e = du_dx + dv_dy;
        float mx_e  = dp * rx + nu_eff * du * rx2;
        float my_e  = dp * ry + nu_eff * dv * ry2;
        float sh    = du_dy + dv_dx;
        float str_e = 2.0f * (du_dx * du_dx + dv_dy * dv_dy) + sh * sh;

        unsigned pos = atomicAdd(&cur[r >> 7], 1u);   // LDS atomic w/ return
        vals[pos] = make_float4(div_e, mx_e, my_e, str_e);
        rloc[pos] = (unsigned)(r & (NPB - 1));

        smooth += (double)(du * du + dv * dv + dp * dp + dn * dn);
    }

    for (int off = 32; off > 0; off >>= 1)
        smooth += __shfl_down(smooth, off);
    __shared__ double sm[4];
    int lane = threadIdx.x & 63, wv = threadIdx.x >> 6;
    if (lane == 0) sm[wv] = smooth;
    __syncthreads();
    if (threadIdx.x == 0)
        atomicAdd(&smooth_slots[blockIdx.x & 63], sm[0] + sm[1] + sm[2] + sm[3]);
}

// Pass 4: per-bucket LDS accumulation (coalesced payload reads) + fused node
// losses + block reduction. 8 double atomics per bucket total.
__global__ __launch_bounds__(256) void bucket_kernel(
    const float4* __restrict__ vals, const unsigned* __restrict__ rloc,
    const unsigned* __restrict__ base,
    const float4* __restrict__ pred, const float4* __restrict__ tgt,
    const unsigned char* __restrict__ wall, int N, double* __restrict__ d)
{
    int b = blockIdx.x;
    __shared__ float acc[5][NPB];
    for (int i = threadIdx.x; i < 5 * NPB; i += 256) (&acc[0][0])[i] = 0.0f;
    __syncthreads();

    unsigned s = base[b], e = base[b + 1];
    for (unsigned idx = s + threadIdx.x; idx < e; idx += 256) {
        float4 v = vals[idx];
        unsigned rl = rloc[idx];
        atomicAdd(&acc[0][rl], 1.0f);
        atomicAdd(&acc[1][rl], v.x);
        atomicAdd(&acc[2][rl], v.y);
        atomicAdd(&acc[3][rl], v.z);
        atomicAdd(&acc[4][rl], v.w);
    }
    __syncthreads();

    double v0 = 0, v1 = 0, v2 = 0, v3 = 0, v4 = 0, v5 = 0, v6 = 0, v7 = 0;
    int i = threadIdx.x;
    int n = b * NPB + i;
    if (i < NPB && n < N) {
        float4 p = pred[n];
        float4 t = tgt[n];
        float inv = 1.0f / fmaxf(acc[0][i], 1.0f);
        float div = acc[1][i] * inv;
        float mx  = acc[2][i] * inv;
        float my  = acc[3][i] * inv;
        float sn  = acc[4][i] * inv;
        float prod = p.w * sn;
        float m = wall[n] ? 1.0f : 0.0f;
        float e0 = p.x - t.x, e1 = p.y - t.y, e2 = p.z - t.z, e3 = p.w - t.w;
        float uv = p.x * p.x + p.y * p.y;
        v0 = (double)(e0 * e0 + e1 * e1 + e2 * e2 + e3 * e3);
        v1 = (double)div * (double)div;
        v2 = (double)mx * (double)mx + (double)my * (double)my;
        v3 = (double)prod * (double)prod;
        v4 = (double)p.w * (double)p.w;
        v5 = (double)m;
        v6 = (double)(m * uv);
        v7 = (double)(m * (uv + p.w * p.w));
    }
    for (int off = 32; off > 0; off >>= 1) {
        v0 += __shfl_down(v0, off); v1 += __shfl_down(v1, off);
        v2 += __shfl_down(v2, off); v3 += __shfl_down(v3, off);
        v4 += __shfl_down(v4, off); v5 += __shfl_down(v5, off);
        v6 += __shfl_down(v6, off); v7 += __shfl_down(v7, off);
    }
    __shared__ double sm[4][8];
    int lane = threadIdx.x & 63, wv = threadIdx.x >> 6;
    if (lane == 0) {
        sm[wv][0] = v0; sm[wv][1] = v1; sm[wv][2] = v2; sm[wv][3] = v3;
        sm[wv][4] = v4; sm[wv][5] = v5; sm[wv][6] = v6; sm[wv][7] = v7;
    }
    __syncthreads();
    if (threadIdx.x < 8) {
        int q = threadIdx.x;
        atomicAdd(&d[q], sm[0][q] + sm[1][q] + sm[2][q] + sm[3][q]);
    }
}

// ===================== fallback path (R1, known-correct) =====================

__global__ __launch_bounds__(256) void edge_kernel(
    const void* __restrict__ eidx, const float2* __restrict__ eattr,
    const float4* __restrict__ pred, int E, int N, const int* __restrict__ flag,
    float* __restrict__ a_cnt, float* __restrict__ a_div,
    float* __restrict__ a_mx, float* __restrict__ a_my,
    float* __restrict__ a_str, double* __restrict__ smooth_slots)
{
    const int is64 = *flag;
    const long long* ll = (const long long*)eidx;
    const int* ii = (const int*)eidx;
    double smooth = 0.0;
    const int stride = gridDim.x * blockDim.x;
    for (int e = blockIdx.x * blockDim.x + threadIdx.x; e < E; e += stride) {
        int row, col;
        if (is64) { row = (int)ll[e]; col = (int)ll[(long long)E + e]; }
        else      { row = ii[e];      col = ii[E + e]; }
        row = min(max(row, 0), N - 1);
        col = min(max(col, 0), N - 1);
        float2 dxy = eattr[e];
        float4 pr = pred[row];
        float4 pc = pred[col];
        float du = pc.x - pr.x, dv = pc.y - pr.y;
        float dp = pc.z - pr.z, dn = pc.w - pr.w;
        float rx  = 1.0f / (dxy.x + EPS);
        float ry  = 1.0f / (dxy.y + EPS);
        float rx2 = 1.0f / (dxy.x * dxy.x + EPS);
        float ry2 = 1.0f / (dxy.y * dxy.y + EPS);
        float du_dx = du * rx, du_dy = du * ry;
        float dv_dx = dv * rx, dv_dy = dv * ry;
        float nu_eff = NU_MOL + pr.w;
        atomicAdd(&a_cnt[row], 1.0f);
        atomicAdd(&a_div[row], du_dx + dv_dy);
        atomicAdd(&a_mx[row], dp * rx + nu_eff * du * rx2);
        atomicAdd(&a_my[row], dp * ry + nu_eff * dv * ry2);
        float sh = du_dy + dv_dx;
        atomicAdd(&a_str[row], 2.0f * (du_dx * du_dx + dv_dy * dv_dy) + sh * sh);
        smooth += (double)(du * du + dv * dv + dp * dp + dn * dn);
    }
    for (int off = 32; off > 0; off >>= 1)
        smooth += __shfl_down(smooth, off);
    __shared__ double sm[4];
    int lane = threadIdx.x & 63, wv = threadIdx.x >> 6;
    if (lane == 0) sm[wv] = smooth;
    __syncthreads();
    if (threadIdx.x == 0)
        atomicAdd(&smooth_slots[blockIdx.x & 63], sm[0] + sm[1] + sm[2] + sm[3]);
}

__global__ __launch_bounds__(256) void node_kernel(
    const float4* __restrict__ pred, const float4* __restrict__ tgt,
    const unsigned char* __restrict__ wall, int N,
    const float* __restrict__ a_cnt, const float* __restrict__ a_div,
    const float* __restrict__ a_mx, const float* __restrict__ a_my,
    const float* __restrict__ a_str, double* __restrict__ d)
{
    int i = blockIdx.x * blockDim.x + threadIdx.x;
    double v0 = 0, v1 = 0, v2 = 0, v3 = 0, v4 = 0, v5 = 0, v6 = 0, v7 = 0;
    if (i < N) {
        float4 p = pred[i];
        float4 t = tgt[i];
        float inv = 1.0f / fmaxf(a_cnt[i], 1.0f);
        float div = a_div[i] * inv;
        float mx = a_mx[i] * inv, my = a_my[i] * inv;
        float sn = a_str[i] * inv;
        float prod = p.w * sn;
        float m = wall[i] ? 1.0f : 0.0f;
        float e0 = p.x - t.x, e1 = p.y - t.y, e2 = p.z - t.z, e3 = p.w - t.w;
        float uv = p.x * p.x + p.y * p.y;
        v0 = (double)(e0 * e0 + e1 * e1 + e2 * e2 + e3 * e3);
        v1 = (double)div * (double)div;
        v2 = (double)mx * (double)mx + (double)my * (double)my;
        v3 = (double)prod * (double)prod;
        v4 = (double)p.w * (double)p.w;
        v5 = (double)m;
        v6 = (double)(m * uv);
        v7 = (double)(m * (uv + p.w * p.w));
    }
    for (int off = 32; off > 0; off >>= 1) {
        v0 += __shfl_down(v0, off); v1 += __shfl_down(v1, off);
        v2 += __shfl_down(v2, off); v3 += __shfl_down(v3, off);
        v4 += __shfl_down(v4, off); v5 += __shfl_down(v5, off);
        v6 += __shfl_down(v6, off); v7 += __shfl_down(v7, off);
    }
    __shared__ double sm[4][8];
    int lane = threadIdx.x & 63, wv = threadIdx.x >> 6;
    if (lane == 0) {
        sm[wv][0] = v0; sm[wv][1] = v1; sm[wv][2] = v2; sm[wv][3] = v3;
        sm[wv][4] = v4; sm[wv][5] = v5; sm[wv][6] = v6; sm[wv][7] = v7;
    }
    __syncthreads();
    if (threadIdx.x < 8) {
        int q = threadIdx.x;
        atomicAdd(&d[q], sm[0][q] + sm[1][q] + sm[2][q] + sm[3][q]);
    }
}

// ===================== launch =====================

extern "C" void kernel_launch(void* const* d_in, const int* in_sizes, int n_in,
                              void* d_out, int out_size, void* d_ws, size_t ws_size,
                              hipStream_t stream) {
    const float4* pred = (const float4*)d_in[0];
    const float4* tgt  = (const float4*)d_in[1];
    const float2* eattr = (const float2*)d_in[2];
    const void* eidx = d_in[3];
    const unsigned char* wall = (const unsigned char*)d_in[4];
    int N = in_sizes[0] / 4;
    int E = in_sizes[2] / 2;
    int NB = (N + NPB - 1) / NPB;

    char* ws = (char*)d_ws;
    double* d = (double*)ws;                 // 8 scalars
    double* smooth_slots = d + 8;            // 64 slots
    int* flag = (int*)(ws + 576);

    // fast-path workspace layout
    size_t off = 1024;
    unsigned* counts = (unsigned*)(ws + off); off += (size_t)NB * NBLK * 4;
    unsigned* totals = (unsigned*)(ws + off); off += (size_t)NB * 4;
    unsigned* base   = (unsigned*)(ws + off); off += (size_t)(NB + 1) * 4;
    off = (off + 15) & ~(size_t)15;
    float4* vals     = (float4*)(ws + off);   off += (size_t)E * 16;
    unsigned* rloc   = (unsigned*)(ws + off); off += (size_t)E * 4;
    size_t need_fast = off;

    bool fast = (NB <= MAXNB) && (ws_size >= need_fast);

    if (fast) {
        hipMemsetAsync(d_ws, 0, 1024, stream);
        detect_idx_dtype<<<1, 1, 0, stream>>>(eidx, N, flag);
        count_kernel<<<NBLK, 256, 0, stream>>>(eidx, E, N, NB, flag, counts);
        scan_rows<<<NB, 256, 0, stream>>>(counts, totals);
        scan_totals<<<1, 256, 0, stream>>>(totals, base, NB);
        scatter_kernel<<<NBLK, 256, 0, stream>>>(eidx, eattr, pred, E, N, NB, flag,
                                                 counts, base, vals, rloc, smooth_slots);
        bucket_kernel<<<NB, 256, 0, stream>>>(vals, rloc, base, pred, tgt, wall, N, d);
        finalize_kernel<<<1, 1, 0, stream>>>(d, smooth_slots, N, E, (float*)d_out);
    } else {
        float* arrays = (float*)(ws + 1024);
        float* a_cnt = arrays + (size_t)0 * N;
        float* a_div = arrays + (size_t)1 * N;
        float* a_mx  = arrays + (size_t)2 * N;
        float* a_my  = arrays + (size_t)3 * N;
        float* a_str = arrays + (size_t)4 * N;
        size_t zbytes = 1024 + (size_t)5 * N * sizeof(float);
        hipMemsetAsync(d_ws, 0, zbytes, stream);
        detect_idx_dtype<<<1, 1, 0, stream>>>(eidx, N, flag);
        edge_kernel<<<4096, 256, 0, stream>>>(eidx, eattr, pred, E, N, flag,
                                              a_cnt, a_div, a_mx, a_my, a_str,
                                              smooth_slots);
        node_kernel<<<(N + 255) / 256, 256, 0, stream>>>(pred, tgt, wall, N,
                                                         a_cnt, a_div, a_mx, a_my,
                                                         a_str, d);
        finalize_kernel<<<1, 1, 0, stream>>>(d, smooth_slots, N, E, (float*)d_out);
    }
}

// Round 3
// 590.886 us; speedup vs baseline: 3.8108x; 1.2737x over previous
//
#include <hip/hip_runtime.h>

#define EPS 1e-8f
#define NU_MOL 1.5e-5f
#define NPB 128            // nodes per bucket
#define MAXNB 832          // max buckets (N <= 106496); padded to 1024 for scans
#define NBLK 1024          // edge-chunk blocks for count/scatter
#define CMAX 6656          // max edges per block chunk (E <= 6.815M)

// ===================== common =====================

__global__ void detect_idx_dtype(const void* eidx, int N, int* flag) {
    const long long* ll = (const long long*)eidx;
    int is64 = 1;
    for (int i = 0; i < 16; ++i) {
        long long v = ll[i];
        if (v < 0 || v >= (long long)N) { is64 = 0; break; }
    }
    *flag = is64;
}

__global__ void finalize_kernel(const double* __restrict__ d,
                                const double* __restrict__ smooth_slots,
                                int N, int E, float* __restrict__ out)
{
    double smooth = 0.0;
    for (int i = 0; i < 64; ++i) smooth += smooth_slots[i];
    double dN = (double)N;
    double n_wall = d[5] > 1.0 ? d[5] : 1.0;
    double total = 1.0  * d[0] / (4.0 * dN)
                 + 0.1  * d[1] / dN
                 + 0.1  * d[2] / dN
                 + 0.05 * d[3] / dN
                 + 0.05 * d[4] / dN
                 + 0.05 * d[6] / n_wall
                 + 0.01 * smooth / (4.0 * (double)E)
                 + 0.02 * d[7] / n_wall;
    out[0] = (float)total;
}

// ===================== fast path =====================

// Pass 1: per-(bucket, block) edge counts via LDS histogram.
__global__ __launch_bounds__(256) void count_kernel(
    const void* __restrict__ eidx, int E, int N, int NB,
    const int* __restrict__ flag, unsigned* __restrict__ counts /* [NB][NBLK] */)
{
    __shared__ unsigned hist[MAXNB];
    for (int i = threadIdx.x; i < NB; i += 256) hist[i] = 0u;
    __syncthreads();
    const int is64 = *flag;
    const long long* ll = (const long long*)eidx;
    const int* ii = (const int*)eidx;
    int chunk = (E + NBLK - 1) / NBLK;
    int s = blockIdx.x * chunk;
    int eend = min(E, s + chunk);
    for (int e = s + (int)threadIdx.x; e < eend; e += 256) {
        int r = is64 ? (int)ll[e] : ii[e];
        r = min(max(r, 0), N - 1);
        atomicAdd(&hist[r >> 7], 1u);
    }
    __syncthreads();
    for (int b = threadIdx.x; b < NB; b += 256)
        counts[(size_t)b * NBLK + blockIdx.x] = hist[b];
}

// Pass 2a: per-bucket exclusive scan over the NBLK block-counts (in place).
__global__ __launch_bounds__(256) void scan_rows(
    unsigned* __restrict__ counts, unsigned* __restrict__ totals)
{
    unsigned* rowp = counts + (size_t)blockIdx.x * NBLK;
    int t = threadIdx.x;
    uint4 v = ((const uint4*)rowp)[t];
    unsigned s = v.x + v.y + v.z + v.w;
    __shared__ unsigned sc[256];
    sc[t] = s; __syncthreads();
    for (int off = 1; off < 256; off <<= 1) {
        unsigned x = (t >= off) ? sc[t - off] : 0u;
        __syncthreads();
        sc[t] += x;
        __syncthreads();
    }
    unsigned ex = sc[t] - s;
    uint4 o;
    o.x = ex; ex += v.x;
    o.y = ex; ex += v.y;
    o.z = ex; ex += v.z;
    o.w = ex;
    ((uint4*)rowp)[t] = o;
    if (t == 255) totals[blockIdx.x] = sc[255];
}

// Pass 2b: exclusive scan of bucket totals -> base[NB+1].
__global__ __launch_bounds__(256) void scan_totals(
    const unsigned* __restrict__ totals, unsigned* __restrict__ base, int NB)
{
    int t = threadIdx.x;
    unsigned v[4]; unsigned s = 0;
    #pragma unroll
    for (int j = 0; j < 4; ++j) {
        int i = t * 4 + j;
        v[j] = (i < NB) ? totals[i] : 0u;
        s += v[j];
    }
    __shared__ unsigned sc[256];
    sc[t] = s; __syncthreads();
    for (int off = 1; off < 256; off <<= 1) {
        unsigned x = (t >= off) ? sc[t - off] : 0u;
        __syncthreads();
        sc[t] += x;
        __syncthreads();
    }
    unsigned ex = sc[t] - s;
    #pragma unroll
    for (int j = 0; j < 4; ++j) {
        int i = t * 4 + j;
        if (i < NB) base[i] = ex;
        ex += v[j];
    }
    if (t == 255) base[NB] = sc[255];
}

// Pass 3: block-local counting sort, then COALESCED payload writes.
// Global layout identical to R2 (bucket-major, per-block subsegments), but
// each block's writes are sequential runs instead of scattered cursors.
__global__ __launch_bounds__(256) void sort_scatter_kernel(
    const void* __restrict__ eidx, const float2* __restrict__ eattr,
    const float4* __restrict__ pred, int E, int N, int NB,
    const int* __restrict__ flag,
    const unsigned* __restrict__ localoff /* counts after scan */,
    const unsigned* __restrict__ base,
    float4* __restrict__ vals, unsigned* __restrict__ rloc,
    double* __restrict__ smooth_slots)
{
    __shared__ unsigned hist[1024];     // histogram -> exclusive scan (scan0)
    __shared__ unsigned cur[1024];      // working cursors for phase B
    __shared__ unsigned gbase[1024];    // global write base per bucket
    __shared__ unsigned rows[CMAX];
    __shared__ unsigned short perm[CMAX];
    __shared__ unsigned sc[256];
    __shared__ double sm[4];

    const int t = threadIdx.x;
    const int blk = blockIdx.x;
    const int is64 = *flag;
    const long long* ll = (const long long*)eidx;
    const int* ii = (const int*)eidx;
    const int chunk = (E + NBLK - 1) / NBLK;
    const int s = blk * chunk;
    const int Cb = min(chunk, E - s);

    for (int i = t; i < 1024; i += 256) hist[i] = 0u;
    __syncthreads();

    // Phase A: coalesced row read -> LDS; histogram; fetch global bases.
    for (int i = t; i < Cb; i += 256) {
        int r = is64 ? (int)ll[s + i] : ii[s + i];
        r = min(max(r, 0), N - 1);
        rows[i] = (unsigned)r;
        atomicAdd(&hist[r >> 7], 1u);
    }
    for (int b = t; b < NB; b += 256)
        gbase[b] = base[b] + localoff[(size_t)b * NBLK + blk];
    __syncthreads();

    // Local exclusive scan of hist[0..1023] (in place), 4 entries/thread.
    unsigned h0 = hist[t * 4 + 0], h1 = hist[t * 4 + 1];
    unsigned h2 = hist[t * 4 + 2], h3 = hist[t * 4 + 3];
    unsigned psum = h0 + h1 + h2 + h3;
    sc[t] = psum; __syncthreads();
    for (int off = 1; off < 256; off <<= 1) {
        unsigned x = (t >= off) ? sc[t - off] : 0u;
        __syncthreads();
        sc[t] += x;
        __syncthreads();
    }
    unsigned ex = sc[t] - psum;
    hist[t * 4 + 0] = ex;            ex += h0;
    hist[t * 4 + 1] = ex;            ex += h1;
    hist[t * 4 + 2] = ex;            ex += h2;
    hist[t * 4 + 3] = ex;
    cur[t * 4 + 0] = hist[t * 4 + 0];
    cur[t * 4 + 1] = hist[t * 4 + 1];
    cur[t * 4 + 2] = hist[t * 4 + 2];
    cur[t * 4 + 3] = hist[t * 4 + 3];
    __syncthreads();

    // Phase B: build permutation via LDS cursors.
    for (int i = t; i < Cb; i += 256) {
        unsigned b = rows[i] >> 7;
        unsigned pos = atomicAdd(&cur[b], 1u);
        perm[pos] = (unsigned short)i;
    }
    __syncthreads();

    // Phase C: sorted walk; gathers confined to this block's hot window;
    // stores coalesced.
    double smooth = 0.0;
    for (int p = t; p < Cb; p += 256) {
        int i = (int)perm[p];
        int e = s + i;
        int r = (int)rows[i];
        int c = is64 ? (int)ll[(long long)E + e] : ii[E + e];
        c = min(max(c, 0), N - 1);
        float2 dxy = eattr[e];
        float4 pr = pred[r];
        float4 pc = pred[c];
        float du = pc.x - pr.x, dv = pc.y - pr.y;
        float dp = pc.z - pr.z, dn = pc.w - pr.w;
        float rx  = 1.0f / (dxy.x + EPS);
        float ry  = 1.0f / (dxy.y + EPS);
        float rx2 = 1.0f / (dxy.x * dxy.x + EPS);
        float ry2 = 1.0f / (dxy.y * dxy.y + EPS);
        float du_dx = du * rx, du_dy = du * ry;
        float dv_dx = dv * rx, dv_dy = dv * ry;
        float nu_eff = NU_MOL + pr.w;
        float div_e = du_dx + dv_dy;
        float mx_e  = dp * rx + nu_eff * du * rx2;
        float my_e  = dp * ry + nu_eff * dv * ry2;
        float sh    = du_dy + dv_dx;
        float str_e = 2.0f * (du_dx * du_dx + dv_dy * dv_dy) + sh * sh;

        unsigned b = (unsigned)r >> 7;
        unsigned wpos = gbase[b] + (unsigned)p - hist[b];  // hist = scan0
        vals[wpos] = make_float4(div_e, mx_e, my_e, str_e);
        rloc[wpos] = (unsigned)(r & (NPB - 1));

        smooth += (double)(du * du + dv * dv + dp * dp + dn * dn);
    }

    for (int off = 32; off > 0; off >>= 1)
        smooth += __shfl_down(smooth, off);
    int lane = t & 63, wv = t >> 6;
    if (lane == 0) sm[wv] = smooth;
    __syncthreads();
    if (t == 0)
        atomicAdd(&smooth_slots[blk & 63], sm[0] + sm[1] + sm[2] + sm[3]);
}

// Pass 4: per-bucket LDS accumulation + fused node losses.
__global__ __launch_bounds__(256) void bucket_kernel(
    const float4* __restrict__ vals, const unsigned* __restrict__ rloc,
    const unsigned* __restrict__ base,
    const float4* __restrict__ pred, const float4* __restrict__ tgt,
    const unsigned char* __restrict__ wall, int N, double* __restrict__ d)
{
    int b = blockIdx.x;
    __shared__ float acc[5][NPB];
    for (int i = threadIdx.x; i < 5 * NPB; i += 256) (&acc[0][0])[i] = 0.0f;
    __syncthreads();

    unsigned s = base[b], e = base[b + 1];
    for (unsigned idx = s + threadIdx.x; idx < e; idx += 256) {
        float4 v = vals[idx];
        unsigned rl = rloc[idx];
        atomicAdd(&acc[0][rl], 1.0f);
        atomicAdd(&acc[1][rl], v.x);
        atomicAdd(&acc[2][rl], v.y);
        atomicAdd(&acc[3][rl], v.z);
        atomicAdd(&acc[4][rl], v.w);
    }
    __syncthreads();

    double v0 = 0, v1 = 0, v2 = 0, v3 = 0, v4 = 0, v5 = 0, v6 = 0, v7 = 0;
    int i = threadIdx.x;
    int n = b * NPB + i;
    if (i < NPB && n < N) {
        float4 p = pred[n];
        float4 t = tgt[n];
        float inv = 1.0f / fmaxf(acc[0][i], 1.0f);
        float div = acc[1][i] * inv;
        float mx  = acc[2][i] * inv;
        float my  = acc[3][i] * inv;
        float sn  = acc[4][i] * inv;
        float prod = p.w * sn;
        float m = wall[n] ? 1.0f : 0.0f;
        float e0 = p.x - t.x, e1 = p.y - t.y, e2 = p.z - t.z, e3 = p.w - t.w;
        float uv = p.x * p.x + p.y * p.y;
        v0 = (double)(e0 * e0 + e1 * e1 + e2 * e2 + e3 * e3);
        v1 = (double)div * (double)div;
        v2 = (double)mx * (double)mx + (double)my * (double)my;
        v3 = (double)prod * (double)prod;
        v4 = (double)p.w * (double)p.w;
        v5 = (double)m;
        v6 = (double)(m * uv);
        v7 = (double)(m * (uv + p.w * p.w));
    }
    for (int off = 32; off > 0; off >>= 1) {
        v0 += __shfl_down(v0, off); v1 += __shfl_down(v1, off);
        v2 += __shfl_down(v2, off); v3 += __shfl_down(v3, off);
        v4 += __shfl_down(v4, off); v5 += __shfl_down(v5, off);
        v6 += __shfl_down(v6, off); v7 += __shfl_down(v7, off);
    }
    __shared__ double sm[4][8];
    int lane = threadIdx.x & 63, wv = threadIdx.x >> 6;
    if (lane == 0) {
        sm[wv][0] = v0; sm[wv][1] = v1; sm[wv][2] = v2; sm[wv][3] = v3;
        sm[wv][4] = v4; sm[wv][5] = v5; sm[wv][6] = v6; sm[wv][7] = v7;
    }
    __syncthreads();
    if (threadIdx.x < 8) {
        int q = threadIdx.x;
        atomicAdd(&d[q], sm[0][q] + sm[1][q] + sm[2][q] + sm[3][q]);
    }
}

// ===================== fallback path (R1-style, known-correct) =====================

__global__ __launch_bounds__(256) void edge_kernel(
    const void* __restrict__ eidx, const float2* __restrict__ eattr,
    const float4* __restrict__ pred, int E, int N, const int* __restrict__ flag,
    float* __restrict__ a_cnt, float* __restrict__ a_div,
    float* __restrict__ a_mx, float* __restrict__ a_my,
    float* __restrict__ a_str, double* __restrict__ smooth_slots)
{
    const int is64 = *flag;
    const long long* ll = (const long long*)eidx;
    const int* ii = (const int*)eidx;
    double smooth = 0.0;
    const int stride = gridDim.x * blockDim.x;
    for (int e = blockIdx.x * blockDim.x + threadIdx.x; e < E; e += stride) {
        int row, col;
        if (is64) { row = (int)ll[e]; col = (int)ll[(long long)E + e]; }
        else      { row = ii[e];      col = ii[E + e]; }
        row = min(max(row, 0), N - 1);
        col = min(max(col, 0), N - 1);
        float2 dxy = eattr[e];
        float4 pr = pred[row];
        float4 pc = pred[col];
        float du = pc.x - pr.x, dv = pc.y - pr.y;
        float dp = pc.z - pr.z, dn = pc.w - pr.w;
        float rx  = 1.0f / (dxy.x + EPS);
        float ry  = 1.0f / (dxy.y + EPS);
        float rx2 = 1.0f / (dxy.x * dxy.x + EPS);
        float ry2 = 1.0f / (dxy.y * dxy.y + EPS);
        float du_dx = du * rx, du_dy = du * ry;
        float dv_dx = dv * rx, dv_dy = dv * ry;
        float nu_eff = NU_MOL + pr.w;
        atomicAdd(&a_cnt[row], 1.0f);
        atomicAdd(&a_div[row], du_dx + dv_dy);
        atomicAdd(&a_mx[row], dp * rx + nu_eff * du * rx2);
        atomicAdd(&a_my[row], dp * ry + nu_eff * dv * ry2);
        float sh = du_dy + dv_dx;
        atomicAdd(&a_str[row], 2.0f * (du_dx * du_dx + dv_dy * dv_dy) + sh * sh);
        smooth += (double)(du * du + dv * dv + dp * dp + dn * dn);
    }
    for (int off = 32; off > 0; off >>= 1)
        smooth += __shfl_down(smooth, off);
    __shared__ double sm[4];
    int lane = threadIdx.x & 63, wv = threadIdx.x >> 6;
    if (lane == 0) sm[wv] = smooth;
    __syncthreads();
    if (threadIdx.x == 0)
        atomicAdd(&smooth_slots[blockIdx.x & 63], sm[0] + sm[1] + sm[2] + sm[3]);
}

__global__ __launch_bounds__(256) void node_kernel(
    const float4* __restrict__ pred, const float4* __restrict__ tgt,
    const unsigned char* __restrict__ wall, int N,
    const float* __restrict__ a_cnt, const float* __restrict__ a_div,
    const float* __restrict__ a_mx, const float* __restrict__ a_my,
    const float* __restrict__ a_str, double* __restrict__ d)
{
    int i = blockIdx.x * blockDim.x + threadIdx.x;
    double v0 = 0, v1 = 0, v2 = 0, v3 = 0, v4 = 0, v5 = 0, v6 = 0, v7 = 0;
    if (i < N) {
        float4 p = pred[i];
        float4 t = tgt[i];
        float inv = 1.0f / fmaxf(a_cnt[i], 1.0f);
        float div = a_div[i] * inv;
        float mx = a_mx[i] * inv, my = a_my[i] * inv;
        float sn = a_str[i] * inv;
        float prod = p.w * sn;
        float m = wall[i] ? 1.0f : 0.0f;
        float e0 = p.x - t.x, e1 = p.y - t.y, e2 = p.z - t.z, e3 = p.w - t.w;
        float uv = p.x * p.x + p.y * p.y;
        v0 = (double)(e0 * e0 + e1 * e1 + e2 * e2 + e3 * e3);
        v1 = (double)div * (double)div;
        v2 = (double)mx * (double)mx + (double)my * (double)my;
        v3 = (double)prod * (double)prod;
        v4 = (double)p.w * (double)p.w;
        v5 = (double)m;
        v6 = (double)(m * uv);
        v7 = (double)(m * (uv + p.w * p.w));
    }
    for (int off = 32; off > 0; off >>= 1) {
        v0 += __shfl_down(v0, off); v1 += __shfl_down(v1, off);
        v2 += __shfl_down(v2, off); v3 += __shfl_down(v3, off);
        v4 += __shfl_down(v4, off); v5 += __shfl_down(v5, off);
        v6 += __shfl_down(v6, off); v7 += __shfl_down(v7, off);
    }
    __shared__ double sm[4][8];
    int lane = threadIdx.x & 63, wv = threadIdx.x >> 6;
    if (lane == 0) {
        sm[wv][0] = v0; sm[wv][1] = v1; sm[wv][2] = v2; sm[wv][3] = v3;
        sm[wv][4] = v4; sm[wv][5] = v5; sm[wv][6] = v6; sm[wv][7] = v7;
    }
    __syncthreads();
    if (threadIdx.x < 8) {
        int q = threadIdx.x;
        atomicAdd(&d[q], sm[0][q] + sm[1][q] + sm[2][q] + sm[3][q]);
    }
}

// ===================== launch =====================

extern "C" void kernel_launch(void* const* d_in, const int* in_sizes, int n_in,
                              void* d_out, int out_size, void* d_ws, size_t ws_size,
                              hipStream_t stream) {
    const float4* pred = (const float4*)d_in[0];
    const float4* tgt  = (const float4*)d_in[1];
    const float2* eattr = (const float2*)d_in[2];
    const void* eidx = d_in[3];
    const unsigned char* wall = (const unsigned char*)d_in[4];
    int N = in_sizes[0] / 4;
    int E = in_sizes[2] / 2;
    int NB = (N + NPB - 1) / NPB;
    int chunk = (E + NBLK - 1) / NBLK;

    char* ws = (char*)d_ws;
    double* d = (double*)ws;                 // 8 scalars
    double* smooth_slots = d + 8;            // 64 slots
    int* flag = (int*)(ws + 576);

    size_t off = 1024;
    unsigned* counts = (unsigned*)(ws + off); off += (size_t)NB * NBLK * 4;
    unsigned* totals = (unsigned*)(ws + off); off += (size_t)NB * 4;
    unsigned* base   = (unsigned*)(ws + off); off += (size_t)(NB + 1) * 4;
    off = (off + 15) & ~(size_t)15;
    float4* vals     = (float4*)(ws + off);   off += (size_t)E * 16;
    unsigned* rloc   = (unsigned*)(ws + off); off += (size_t)E * 4;
    size_t need_fast = off;

    bool fast = (NB <= MAXNB) && (chunk <= CMAX) && (ws_size >= need_fast);

    if (fast) {
        hipMemsetAsync(d_ws, 0, 1024, stream);
        detect_idx_dtype<<<1, 1, 0, stream>>>(eidx, N, flag);
        count_kernel<<<NBLK, 256, 0, stream>>>(eidx, E, N, NB, flag, counts);
        scan_rows<<<NB, 256, 0, stream>>>(counts, totals);
        scan_totals<<<1, 256, 0, stream>>>(totals, base, NB);
        sort_scatter_kernel<<<NBLK, 256, 0, stream>>>(eidx, eattr, pred, E, N, NB,
                                                      flag, counts, base, vals, rloc,
                                                      smooth_slots);
        bucket_kernel<<<NB, 256, 0, stream>>>(vals, rloc, base, pred, tgt, wall, N, d);
        finalize_kernel<<<1, 1, 0, stream>>>(d, smooth_slots, N, E, (float*)d_out);
    } else {
        float* arrays = (float*)(ws + 1024);
        float* a_cnt = arrays + (size_t)0 * N;
        float* a_div = arrays + (size_t)1 * N;
        float* a_mx  = arrays + (size_t)2 * N;
        float* a_my  = arrays + (size_t)3 * N;
        float* a_str = arrays + (size_t)4 * N;
        size_t zbytes = 1024 + (size_t)5 * N * sizeof(float);
        hipMemsetAsync(d_ws, 0, zbytes, stream);
        detect_idx_dtype<<<1, 1, 0, stream>>>(eidx, N, flag);
        edge_kernel<<<4096, 256, 0, stream>>>(eidx, eattr, pred, E, N, flag,
                                              a_cnt, a_div, a_mx, a_my, a_str,
                                              smooth_slots);
        node_kernel<<<(N + 255) / 256, 256, 0, stream>>>(pred, tgt, wall, N,
                                                         a_cnt, a_div, a_mx, a_my,
                                                         a_str, d);
        finalize_kernel<<<1, 1, 0, stream>>>(d, smooth_slots, N, E, (float*)d_out);
    }
}

// Round 4
// 583.102 us; speedup vs baseline: 3.8616x; 1.0133x over previous
//
#include <hip/hip_runtime.h>

#define EPS 1e-8f
#define NU_MOL 1.5e-5f
#define NPB 128            // nodes per bucket
#define MAXNB 832          // max buckets (N <= 106496); tables padded to 1024
#define NBLK 2048          // edge-chunk blocks for count/scatter
#define CMAX 3328          // max edges per block chunk (E <= 6.81M)

// ===================== common =====================

__global__ void detect_idx_dtype(const void* eidx, int N, int* flag) {
    const long long* ll = (const long long*)eidx;
    int is64 = 1;
    for (int i = 0; i < 16; ++i) {
        long long v = ll[i];
        if (v < 0 || v >= (long long)N) { is64 = 0; break; }
    }
    *flag = is64;
}

__global__ void finalize_kernel(const double* __restrict__ d,
                                const double* __restrict__ smooth_slots,
                                int N, int E, float* __restrict__ out)
{
    double smooth = 0.0;
    for (int i = 0; i < 64; ++i) smooth += smooth_slots[i];
    double dN = (double)N;
    double n_wall = d[5] > 1.0 ? d[5] : 1.0;
    double total = 1.0  * d[0] / (4.0 * dN)
                 + 0.1  * d[1] / dN
                 + 0.1  * d[2] / dN
                 + 0.05 * d[3] / dN
                 + 0.05 * d[4] / dN
                 + 0.05 * d[6] / n_wall
                 + 0.01 * smooth / (4.0 * (double)E)
                 + 0.02 * d[7] / n_wall;
    out[0] = (float)total;
}

// ===================== fast path =====================

// Pass 1: per-(bucket, block) edge counts via LDS histogram.
__global__ __launch_bounds__(256) void count_kernel(
    const void* __restrict__ eidx, int E, int N, int NB,
    const int* __restrict__ flag, unsigned* __restrict__ counts /* [NB][NBLK] */)
{
    __shared__ unsigned hist[1024];
    for (int i = threadIdx.x; i < 1024; i += 256) hist[i] = 0u;
    __syncthreads();
    const int is64 = *flag;
    const long long* ll = (const long long*)eidx;
    const int* ii = (const int*)eidx;
    int chunk = (E + NBLK - 1) / NBLK;
    int s = blockIdx.x * chunk;
    int eend = min(E, s + chunk);
    for (int e = s + (int)threadIdx.x; e < eend; e += 256) {
        int r = is64 ? (int)ll[e] : ii[e];
        r = min(max(r, 0), N - 1);
        atomicAdd(&hist[r >> 7], 1u);
    }
    __syncthreads();
    for (int b = threadIdx.x; b < NB; b += 256)
        counts[(size_t)b * NBLK + blockIdx.x] = hist[b];
}

// Pass 2a: per-bucket exclusive scan over the NBLK block-counts (in place).
__global__ __launch_bounds__(256) void scan_rows(
    unsigned* __restrict__ counts, unsigned* __restrict__ totals)
{
    const int K = NBLK / 256;
    unsigned* rowp = counts + (size_t)blockIdx.x * NBLK;
    int t = threadIdx.x;
    unsigned v[K];
    unsigned s = 0;
    #pragma unroll
    for (int j = 0; j < K; ++j) { v[j] = rowp[t * K + j]; s += v[j]; }
    __shared__ unsigned sc[256];
    sc[t] = s; __syncthreads();
    for (int off = 1; off < 256; off <<= 1) {
        unsigned x = (t >= off) ? sc[t - off] : 0u;
        __syncthreads();
        sc[t] += x;
        __syncthreads();
    }
    unsigned ex = sc[t] - s;
    #pragma unroll
    for (int j = 0; j < K; ++j) { rowp[t * K + j] = ex; ex += v[j]; }
    if (t == 255) totals[blockIdx.x] = sc[255];
}

// Pass 2b: exclusive scan of bucket totals -> base[NB+1].
__global__ __launch_bounds__(256) void scan_totals(
    const unsigned* __restrict__ totals, unsigned* __restrict__ base, int NB)
{
    int t = threadIdx.x;
    unsigned v[4]; unsigned s = 0;
    #pragma unroll
    for (int j = 0; j < 4; ++j) {
        int i = t * 4 + j;
        v[j] = (i < NB) ? totals[i] : 0u;
        s += v[j];
    }
    __shared__ unsigned sc[256];
    sc[t] = s; __syncthreads();
    for (int off = 1; off < 256; off <<= 1) {
        unsigned x = (t >= off) ? sc[t - off] : 0u;
        __syncthreads();
        sc[t] += x;
        __syncthreads();
    }
    unsigned ex = sc[t] - s;
    #pragma unroll
    for (int j = 0; j < 4; ++j) {
        int i = t * 4 + j;
        if (i < NB) base[i] = ex;
        ex += v[j];
    }
    if (t == 255) base[NB] = sc[255];
}

// Pass 3: block-local counting sort (packed u32 records, lean LDS) +
// coalesced payload writes.
__global__ __launch_bounds__(256) void sort_scatter_kernel(
    const void* __restrict__ eidx, const float2* __restrict__ eattr,
    const float4* __restrict__ pred, int E, int N, int NB,
    const int* __restrict__ flag,
    const unsigned* __restrict__ localoff /* counts after scan */,
    const unsigned* __restrict__ base,
    float4* __restrict__ vals, unsigned char* __restrict__ rl8,
    double* __restrict__ smooth_slots)
{
    __shared__ unsigned hist[1024];     // histogram -> exclusive scan (scan0)
    __shared__ unsigned cur[1024];      // working cursors for phase B
    __shared__ unsigned gbase[1024];    // global write base per bucket (adjusted)
    __shared__ unsigned pk[CMAX];       // packed (b<<20)|(rl<<13)|i ; aliases sc
    __shared__ double sm[4];
    unsigned* sc = pk;                  // scan scratch (only used before pk writes)

    const int t = threadIdx.x;
    const int blk = blockIdx.x;
    const int is64 = *flag;
    const long long* ll = (const long long*)eidx;
    const int* ii = (const int*)eidx;
    const int chunk = (E + NBLK - 1) / NBLK;
    const int s = blk * chunk;
    const int Cb = min(chunk, E - s);

    for (int i = t; i < 1024; i += 256) hist[i] = 0u;
    __syncthreads();

    // Phase A: coalesced row read; histogram; fetch global bases.
    for (int i = t; i < Cb; i += 256) {
        int r = is64 ? (int)ll[s + i] : ii[s + i];
        r = min(max(r, 0), N - 1);
        atomicAdd(&hist[r >> 7], 1u);
    }
    for (int b = t; b < NB; b += 256)
        gbase[b] = base[b] + localoff[(size_t)b * NBLK + blk];
    __syncthreads();

    // Local exclusive scan of hist[0..1023] (in place), 4 entries/thread.
    unsigned h0 = hist[t * 4 + 0], h1 = hist[t * 4 + 1];
    unsigned h2 = hist[t * 4 + 2], h3 = hist[t * 4 + 3];
    unsigned psum = h0 + h1 + h2 + h3;
    __syncthreads();           // hist reads done before sc (=pk) reuse is safe
    sc[t] = psum; __syncthreads();
    for (int off = 1; off < 256; off <<= 1) {
        unsigned x = (t >= off) ? sc[t - off] : 0u;
        __syncthreads();
        sc[t] += x;
        __syncthreads();
    }
    unsigned ex = sc[t] - psum;
    __syncthreads();           // all sc reads done before pk writes
    hist[t * 4 + 0] = ex;  cur[t * 4 + 0] = ex;  ex += h0;
    hist[t * 4 + 1] = ex;  cur[t * 4 + 1] = ex;  ex += h1;
    hist[t * 4 + 2] = ex;  cur[t * 4 + 2] = ex;  ex += h2;
    hist[t * 4 + 3] = ex;  cur[t * 4 + 3] = ex;
    __syncthreads();

    // Phase B: re-read rows (L1-hot, 26KB window), build packed records.
    for (int i = t; i < Cb; i += 256) {
        int r = is64 ? (int)ll[s + i] : ii[s + i];
        r = min(max(r, 0), N - 1);
        unsigned b = (unsigned)r >> 7;
        unsigned pos = atomicAdd(&cur[b], 1u);
        pk[pos] = (b << 20) | ((unsigned)(r & (NPB - 1)) << 13) | (unsigned)i;
    }
    __syncthreads();

    // Adjust gbase so wpos = gbase[b] + p  (subtract scan0).
    for (int b = t; b < NB; b += 256) gbase[b] -= hist[b];
    __syncthreads();

    // Phase C: sorted walk; coalesced stores; gathers in small hot windows.
    double smooth = 0.0;
    for (int p = t; p < Cb; p += 256) {
        unsigned v = pk[p];
        int i = (int)(v & 0x1FFFu);
        unsigned rl = (v >> 13) & 0x7Fu;
        unsigned b = v >> 20;
        int e = s + i;
        int r = (int)((b << 7) | rl);
        int c = is64 ? (int)ll[(long long)E + e] : ii[E + e];
        c = min(max(c, 0), N - 1);
        float2 dxy = eattr[e];
        float4 pr = pred[r];
        float4 pc = pred[c];
        float du = pc.x - pr.x, dv = pc.y - pr.y;
        float dp = pc.z - pr.z, dn = pc.w - pr.w;
        float rx  = 1.0f / (dxy.x + EPS);
        float ry  = 1.0f / (dxy.y + EPS);
        float rx2 = 1.0f / (dxy.x * dxy.x + EPS);
        float ry2 = 1.0f / (dxy.y * dxy.y + EPS);
        float du_dx = du * rx, du_dy = du * ry;
        float dv_dx = dv * rx, dv_dy = dv * ry;
        float nu_eff = NU_MOL + pr.w;
        float div_e = du_dx + dv_dy;
        float mx_e  = dp * rx + nu_eff * du * rx2;
        float my_e  = dp * ry + nu_eff * dv * ry2;
        float sh    = du_dy + dv_dx;
        float str_e = 2.0f * (du_dx * du_dx + dv_dy * dv_dy) + sh * sh;

        unsigned wpos = gbase[b] + (unsigned)p;
        vals[wpos] = make_float4(div_e, mx_e, my_e, str_e);
        rl8[wpos] = (unsigned char)rl;

        smooth += (double)(du * du + dv * dv + dp * dp + dn * dn);
    }

    for (int off = 32; off > 0; off >>= 1)
        smooth += __shfl_down(smooth, off);
    int lane = t & 63, wv = t >> 6;
    if (lane == 0) sm[wv] = smooth;
    __syncthreads();
    if (t == 0)
        atomicAdd(&smooth_slots[blk & 63], sm[0] + sm[1] + sm[2] + sm[3]);
}

// Pass 4: per-bucket accumulation with PER-WAVE private LDS accumulators
// (no inter-wave same-address serialization) + fused node losses.
__global__ __launch_bounds__(512) void bucket_kernel(
    const float4* __restrict__ vals, const unsigned char* __restrict__ rl8,
    const unsigned* __restrict__ base,
    const float4* __restrict__ pred, const float4* __restrict__ tgt,
    const unsigned char* __restrict__ wall, int N, double* __restrict__ d)
{
    int b = blockIdx.x;
    __shared__ float acc[8][5][NPB];    // 8 waves x 5 quantities x 128 nodes
    for (int i = threadIdx.x; i < 8 * 5 * NPB; i += 512) (&acc[0][0][0])[i] = 0.0f;
    __syncthreads();

    int wv = threadIdx.x >> 6;
    unsigned s = base[b], e = base[b + 1];
    for (unsigned idx = s + threadIdx.x; idx < e; idx += 512) {
        float4 v = vals[idx];
        unsigned rl = rl8[idx];
        atomicAdd(&acc[wv][0][rl], 1.0f);
        atomicAdd(&acc[wv][1][rl], v.x);
        atomicAdd(&acc[wv][2][rl], v.y);
        atomicAdd(&acc[wv][3][rl], v.z);
        atomicAdd(&acc[wv][4][rl], v.w);
    }
    __syncthreads();

    double v0 = 0, v1 = 0, v2 = 0, v3 = 0, v4 = 0, v5 = 0, v6 = 0, v7 = 0;
    int i = threadIdx.x;
    int n = b * NPB + i;
    if (i < NPB && n < N) {
        float cnt = 0, sdiv = 0, smx = 0, smy = 0, sstr = 0;
        #pragma unroll
        for (int w = 0; w < 8; ++w) {
            cnt += acc[w][0][i]; sdiv += acc[w][1][i]; smx += acc[w][2][i];
            smy += acc[w][3][i]; sstr += acc[w][4][i];
        }
        float4 p = pred[n];
        float4 t = tgt[n];
        float inv = 1.0f / fmaxf(cnt, 1.0f);
        float div = sdiv * inv;
        float mx  = smx * inv;
        float my  = smy * inv;
        float sn  = sstr * inv;
        float prod = p.w * sn;
        float m = wall[n] ? 1.0f : 0.0f;
        float e0 = p.x - t.x, e1 = p.y - t.y, e2 = p.z - t.z, e3 = p.w - t.w;
        float uv = p.x * p.x + p.y * p.y;
        v0 = (double)(e0 * e0 + e1 * e1 + e2 * e2 + e3 * e3);
        v1 = (double)div * (double)div;
        v2 = (double)mx * (double)mx + (double)my * (double)my;
        v3 = (double)prod * (double)prod;
        v4 = (double)p.w * (double)p.w;
        v5 = (double)m;
        v6 = (double)(m * uv);
        v7 = (double)(m * (uv + p.w * p.w));
    }
    for (int off = 32; off > 0; off >>= 1) {
        v0 += __shfl_down(v0, off); v1 += __shfl_down(v1, off);
        v2 += __shfl_down(v2, off); v3 += __shfl_down(v3, off);
        v4 += __shfl_down(v4, off); v5 += __shfl_down(v5, off);
        v6 += __shfl_down(v6, off); v7 += __shfl_down(v7, off);
    }
    __shared__ double sm[8][8];
    int lane = threadIdx.x & 63;
    if (lane == 0) {
        sm[wv][0] = v0; sm[wv][1] = v1; sm[wv][2] = v2; sm[wv][3] = v3;
        sm[wv][4] = v4; sm[wv][5] = v5; sm[wv][6] = v6; sm[wv][7] = v7;
    }
    __syncthreads();
    if (threadIdx.x < 8) {
        int q = threadIdx.x;
        double tsum = 0;
        #pragma unroll
        for (int w = 0; w < 8; ++w) tsum += sm[w][q];
        atomicAdd(&d[q], tsum);
    }
}

// ===================== fallback path (R1-style, known-correct) =====================

__global__ __launch_bounds__(256) void edge_kernel(
    const void* __restrict__ eidx, const float2* __restrict__ eattr,
    const float4* __restrict__ pred, int E, int N, const int* __restrict__ flag,
    float* __restrict__ a_cnt, float* __restrict__ a_div,
    float* __restrict__ a_mx, float* __restrict__ a_my,
    float* __restrict__ a_str, double* __restrict__ smooth_slots)
{
    const int is64 = *flag;
    const long long* ll = (const long long*)eidx;
    const int* ii = (const int*)eidx;
    double smooth = 0.0;
    const int stride = gridDim.x * blockDim.x;
    for (int e = blockIdx.x * blockDim.x + threadIdx.x; e < E; e += stride) {
        int row, col;
        if (is64) { row = (int)ll[e]; col = (int)ll[(long long)E + e]; }
        else      { row = ii[e];      col = ii[E + e]; }
        row = min(max(row, 0), N - 1);
        col = min(max(col, 0), N - 1);
        float2 dxy = eattr[e];
        float4 pr = pred[row];
        float4 pc = pred[col];
        float du = pc.x - pr.x, dv = pc.y - pr.y;
        float dp = pc.z - pr.z, dn = pc.w - pr.w;
        float rx  = 1.0f / (dxy.x + EPS);
        float ry  = 1.0f / (dxy.y + EPS);
        float rx2 = 1.0f / (dxy.x * dxy.x + EPS);
        float ry2 = 1.0f / (dxy.y * dxy.y + EPS);
        float du_dx = du * rx, du_dy = du * ry;
        float dv_dx = dv * rx, dv_dy = dv * ry;
        float nu_eff = NU_MOL + pr.w;
        atomicAdd(&a_cnt[row], 1.0f);
        atomicAdd(&a_div[row], du_dx + dv_dy);
        atomicAdd(&a_mx[row], dp * rx + nu_eff * du * rx2);
        atomicAdd(&a_my[row], dp * ry + nu_eff * dv * ry2);
        float sh = du_dy + dv_dx;
        atomicAdd(&a_str[row], 2.0f * (du_dx * du_dx + dv_dy * dv_dy) + sh * sh);
        smooth += (double)(du * du + dv * dv + dp * dp + dn * dn);
    }
    for (int off = 32; off > 0; off >>= 1)
        smooth += __shfl_down(smooth, off);
    __shared__ double sm[4];
    int lane = threadIdx.x & 63, wv = threadIdx.x >> 6;
    if (lane == 0) sm[wv] = smooth;
    __syncthreads();
    if (threadIdx.x == 0)
        atomicAdd(&smooth_slots[blockIdx.x & 63], sm[0] + sm[1] + sm[2] + sm[3]);
}

__global__ __launch_bounds__(256) void node_kernel(
    const float4* __restrict__ pred, const float4* __restrict__ tgt,
    const unsigned char* __restrict__ wall, int N,
    const float* __restrict__ a_cnt, const float* __restrict__ a_div,
    const float* __restrict__ a_mx, const float* __restrict__ a_my,
    const float* __restrict__ a_str, double* __restrict__ d)
{
    int i = blockIdx.x * blockDim.x + threadIdx.x;
    double v0 = 0, v1 = 0, v2 = 0, v3 = 0, v4 = 0, v5 = 0, v6 = 0, v7 = 0;
    if (i < N) {
        float4 p = pred[i];
        float4 t = tgt[i];
        float inv = 1.0f / fmaxf(a_cnt[i], 1.0f);
        float div = a_div[i] * inv;
        float mx = a_mx[i] * inv, my = a_my[i] * inv;
        float sn = a_str[i] * inv;
        float prod = p.w * sn;
        float m = wall[i] ? 1.0f : 0.0f;
        float e0 = p.x - t.x, e1 = p.y - t.y, e2 = p.z - t.z, e3 = p.w - t.w;
        float uv = p.x * p.x + p.y * p.y;
        v0 = (double)(e0 * e0 + e1 * e1 + e2 * e2 + e3 * e3);
        v1 = (double)div * (double)div;
        v2 = (double)mx * (double)mx + (double)my * (double)my;
        v3 = (double)prod * (double)prod;
        v4 = (double)p.w * (double)p.w;
        v5 = (double)m;
        v6 = (double)(m * uv);
        v7 = (double)(m * (uv + p.w * p.w));
    }
    for (int off = 32; off > 0; off >>= 1) {
        v0 += __shfl_down(v0, off); v1 += __shfl_down(v1, off);
        v2 += __shfl_down(v2, off); v3 += __shfl_down(v3, off);
        v4 += __shfl_down(v4, off); v5 += __shfl_down(v5, off);
        v6 += __shfl_down(v6, off); v7 += __shfl_down(v7, off);
    }
    __shared__ double sm[4][8];
    int lane = threadIdx.x & 63, wv = threadIdx.x >> 6;
    if (lane == 0) {
        sm[wv][0] = v0; sm[wv][1] = v1; sm[wv][2] = v2; sm[wv][3] = v3;
        sm[wv][4] = v4; sm[wv][5] = v5; sm[wv][6] = v6; sm[wv][7] = v7;
    }
    __syncthreads();
    if (threadIdx.x < 8) {
        int q = threadIdx.x;
        atomicAdd(&d[q], sm[0][q] + sm[1][q] + sm[2][q] + sm[3][q]);
    }
}

// ===================== launch =====================

extern "C" void kernel_launch(void* const* d_in, const int* in_sizes, int n_in,
                              void* d_out, int out_size, void* d_ws, size_t ws_size,
                              hipStream_t stream) {
    const float4* pred = (const float4*)d_in[0];
    const float4* tgt  = (const float4*)d_in[1];
    const float2* eattr = (const float2*)d_in[2];
    const void* eidx = d_in[3];
    const unsigned char* wall = (const unsigned char*)d_in[4];
    int N = in_sizes[0] / 4;
    int E = in_sizes[2] / 2;
    int NB = (N + NPB - 1) / NPB;
    int chunk = (E + NBLK - 1) / NBLK;

    char* ws = (char*)d_ws;
    double* d = (double*)ws;                 // 8 scalars
    double* smooth_slots = d + 8;            // 64 slots
    int* flag = (int*)(ws + 576);

    size_t off = 1024;
    unsigned* counts = (unsigned*)(ws + off); off += (size_t)NB * NBLK * 4;
    unsigned* totals = (unsigned*)(ws + off); off += (size_t)NB * 4;
    unsigned* base   = (unsigned*)(ws + off); off += (size_t)(NB + 1) * 4;
    off = (off + 15) & ~(size_t)15;
    float4* vals     = (float4*)(ws + off);   off += (size_t)E * 16;
    unsigned char* rl8 = (unsigned char*)(ws + off); off += (size_t)E;
    size_t need_fast = off;

    bool fast = (NB <= MAXNB) && (chunk <= CMAX) && (ws_size >= need_fast);

    if (fast) {
        hipMemsetAsync(d_ws, 0, 1024, stream);
        detect_idx_dtype<<<1, 1, 0, stream>>>(eidx, N, flag);
        count_kernel<<<NBLK, 256, 0, stream>>>(eidx, E, N, NB, flag, counts);
        scan_rows<<<NB, 256, 0, stream>>>(counts, totals);
        scan_totals<<<1, 256, 0, stream>>>(totals, base, NB);
        sort_scatter_kernel<<<NBLK, 256, 0, stream>>>(eidx, eattr, pred, E, N, NB,
                                                      flag, counts, base, vals, rl8,
                                                      smooth_slots);
        bucket_kernel<<<NB, 512, 0, stream>>>(vals, rl8, base, pred, tgt, wall, N, d);
        finalize_kernel<<<1, 1, 0, stream>>>(d, smooth_slots, N, E, (float*)d_out);
    } else {
        float* arrays = (float*)(ws + 1024);
        float* a_cnt = arrays + (size_t)0 * N;
        float* a_div = arrays + (size_t)1 * N;
        float* a_mx  = arrays + (size_t)2 * N;
        float* a_my  = arrays + (size_t)3 * N;
        float* a_str = arrays + (size_t)4 * N;
        size_t zbytes = 1024 + (size_t)5 * N * sizeof(float);
        hipMemsetAsync(d_ws, 0, zbytes, stream);
        detect_idx_dtype<<<1, 1, 0, stream>>>(eidx, N, flag);
        edge_kernel<<<4096, 256, 0, stream>>>(eidx, eattr, pred, E, N, flag,
                                              a_cnt, a_div, a_mx, a_my, a_str,
                                              smooth_slots);
        node_kernel<<<(N + 255) / 256, 256, 0, stream>>>(pred, tgt, wall, N,
                                                         a_cnt, a_div, a_mx, a_my,
                                                         a_str, d);
        finalize_kernel<<<1, 1, 0, stream>>>(d, smooth_slots, N, E, (float*)d_out);
    }
}

// Round 5
// 550.473 us; speedup vs baseline: 4.0905x; 1.0593x over previous
//
#include <hip/hip_runtime.h>

#define EPS 1e-8f
#define NU_MOL 1.5e-5f
#define NPB 128            // nodes per bucket
#define MAXNB 832          // max buckets (N <= 106496); tables padded to 1024
#define NBP 1024           // padded row stride of counts matrix (u32 elems)
#define NBLK 2048          // edge-chunk blocks for count/scatter
#define CMAX 3328          // max edges per block chunk (E <= 6.81M)
#define KMAX 13            // CMAX / 256

// ===================== common =====================

__global__ void detect_idx_dtype(const void* eidx, int N, int* flag) {
    const long long* ll = (const long long*)eidx;
    int is64 = 1;
    for (int i = 0; i < 16; ++i) {
        long long v = ll[i];
        if (v < 0 || v >= (long long)N) { is64 = 0; break; }
    }
    *flag = is64;
}

__global__ void finalize_kernel(const double* __restrict__ d,
                                const double* __restrict__ smooth_slots,
                                int N, int E, float* __restrict__ out)
{
    double smooth = 0.0;
    for (int i = 0; i < 64; ++i) smooth += smooth_slots[i];
    double dN = (double)N;
    double n_wall = d[5] > 1.0 ? d[5] : 1.0;
    double total = 1.0  * d[0] / (4.0 * dN)
                 + 0.1  * d[1] / dN
                 + 0.1  * d[2] / dN
                 + 0.05 * d[3] / dN
                 + 0.05 * d[4] / dN
                 + 0.05 * d[6] / n_wall
                 + 0.01 * smooth / (4.0 * (double)E)
                 + 0.02 * d[7] / n_wall;
    out[0] = (float)total;
}

__device__ inline unsigned bf16rne(float f) {
    unsigned u = __float_as_uint(f);
    u += 0x7FFFu + ((u >> 16) & 1u);
    return u >> 16;
}
__device__ inline float bf16dec(unsigned h) {
    return __uint_as_float(h << 16);
}

// ===================== fast path =====================

// Pass 1: per-(block, bucket) edge counts. counts layout: [blk][NBP] — each
// block writes a CONTIGUOUS row (no strided scatter).
__global__ __launch_bounds__(256) void count_kernel(
    const void* __restrict__ eidx, int E, int N, int NB,
    const int* __restrict__ flag, unsigned* __restrict__ counts)
{
    __shared__ unsigned hist[1024];
    for (int i = threadIdx.x; i < 1024; i += 256) hist[i] = 0u;
    __syncthreads();
    const int is64 = *flag;
    const long long* ll = (const long long*)eidx;
    const int* ii = (const int*)eidx;
    int chunk = (E + NBLK - 1) / NBLK;
    int s = blockIdx.x * chunk;
    int eend = min(E, s + chunk);
    for (int e = s + (int)threadIdx.x; e < eend; e += 256) {
        int r = is64 ? (int)ll[e] : ii[e];
        r = min(max(r, 0), N - 1);
        atomicAdd(&hist[r >> 7], 1u);
    }
    __syncthreads();
    for (int b = threadIdx.x; b < NB; b += 256)
        counts[(size_t)blockIdx.x * NBP + b] = hist[b];
}

// Pass 2a: per-bucket exclusive scan across blocks, tiled: each block handles
// 16 buckets, sweeping NBLK rows in 64-row tiles. All loads/stores are 64B
// contiguous row segments. In-place (counts -> local offsets), totals out.
__global__ __launch_bounds__(256) void scan_tiles(
    unsigned* __restrict__ counts, unsigned* __restrict__ totals, int NB)
{
    __shared__ unsigned tile[64][17];
    const int t = threadIdx.x;
    const int b0 = blockIdx.x * 16;
    const int j = t & 15;            // bucket lane
    const int rl = t >> 4;           // row lane (16 rows per load step)
    const bool bok = (b0 + j) < NB;
    unsigned carry = 0;              // live in threads t<16

    for (int c = 0; c < NBLK / 64; ++c) {
        // load 64 rows x 16 buckets
        #pragma unroll
        for (int s_ = 0; s_ < 4; ++s_) {
            int row = c * 64 + s_ * 16 + rl;
            tile[s_ * 16 + rl][j] = bok ? counts[(size_t)row * NBP + b0 + j] : 0u;
        }
        __syncthreads();
        if (t < 16) {
            unsigned cy = carry;
            #pragma unroll
            for (int r = 0; r < 64; ++r) {
                unsigned v = tile[r][t];
                tile[r][t] = cy;
                cy += v;
            }
            carry = cy;
        }
        __syncthreads();
        #pragma unroll
        for (int s_ = 0; s_ < 4; ++s_) {
            int row = c * 64 + s_ * 16 + rl;
            if (bok) counts[(size_t)row * NBP + b0 + j] = tile[s_ * 16 + rl][j];
        }
        __syncthreads();
    }
    if (t < 16 && bok) totals[b0 + t] = carry;
}

// Pass 2b: exclusive scan of bucket totals -> base[NB+1].
__global__ __launch_bounds__(256) void scan_totals(
    const unsigned* __restrict__ totals, unsigned* __restrict__ base, int NB)
{
    int t = threadIdx.x;
    unsigned v[4]; unsigned s = 0;
    #pragma unroll
    for (int j = 0; j < 4; ++j) {
        int i = t * 4 + j;
        v[j] = (i < NB) ? totals[i] : 0u;
        s += v[j];
    }
    __shared__ unsigned sc[256];
    sc[t] = s; __syncthreads();
    for (int off = 1; off < 256; off <<= 1) {
        unsigned x = (t >= off) ? sc[t - off] : 0u;
        __syncthreads();
        sc[t] += x;
        __syncthreads();
    }
    unsigned ex = sc[t] - s;
    #pragma unroll
    for (int j = 0; j < 4; ++j) {
        int i = t * 4 + j;
        if (i < NB) base[i] = ex;
        ex += v[j];
    }
    if (t == 255) base[NB] = sc[255];
}

// Pass 3: rows -> registers; payload computed in SEQUENTIAL edge order
// (all global reads coalesced); permutation applied through LDS staging;
// final stores sequential/coalesced. bf16x4 payload.
__global__ __launch_bounds__(256) void sort_scatter_kernel(
    const void* __restrict__ eidx, const float2* __restrict__ eattr,
    const float4* __restrict__ pred, int E, int N, int NB,
    const int* __restrict__ flag,
    const unsigned* __restrict__ localoff /* counts after scan, [blk][NBP] */,
    const unsigned* __restrict__ base,
    uint2* __restrict__ vals, unsigned char* __restrict__ rl8g,
    double* __restrict__ smooth_slots)
{
    __shared__ unsigned hist[1024];          // histogram -> scan0 (in place)
    __shared__ unsigned cur[1024];           // cursors
    __shared__ unsigned gb2[1024];           // gbase - scan0
    __shared__ uint2 pl[CMAX];               // staged payload (bf16x4)
    __shared__ unsigned short bb[CMAX];      // bucket of sorted slot
    __shared__ unsigned char rls[CMAX];      // rl of sorted slot
    __shared__ unsigned sc[256];
    __shared__ double sm[4];

    const int t = threadIdx.x;
    const int blk = blockIdx.x;
    const int is64 = *flag;
    const long long* ll = (const long long*)eidx;
    const int* ii = (const int*)eidx;
    const int chunk = (E + NBLK - 1) / NBLK;
    const int s = blk * chunk;
    const int Cb = min(chunk, E - s);

    for (int i = t; i < 1024; i += 256) hist[i] = 0u;
    __syncthreads();

    // Phase A: rows -> registers (read ONCE), histogram.
    unsigned rr[KMAX];
    #pragma unroll
    for (int k = 0; k < KMAX; ++k) {
        int i = k * 256 + t;
        if (i < Cb) {
            int r = is64 ? (int)ll[s + i] : ii[s + i];
            r = min(max(r, 0), N - 1);
            rr[k] = (unsigned)r;
            atomicAdd(&hist[r >> 7], 1u);
        } else rr[k] = 0xFFFFFFFFu;
    }
    // gbase (coalesced contiguous row read)
    for (int b = t; b < NB; b += 256)
        gb2[b] = base[b] + localoff[(size_t)blk * NBP + b];
    __syncthreads();

    // exclusive scan of hist[0..1023] in place -> scan0
    unsigned h0 = hist[t * 4 + 0], h1 = hist[t * 4 + 1];
    unsigned h2 = hist[t * 4 + 2], h3 = hist[t * 4 + 3];
    unsigned psum = h0 + h1 + h2 + h3;
    sc[t] = psum; __syncthreads();
    for (int off = 1; off < 256; off <<= 1) {
        unsigned x = (t >= off) ? sc[t - off] : 0u;
        __syncthreads();
        sc[t] += x;
        __syncthreads();
    }
    unsigned ex = sc[t] - psum;
    hist[t * 4 + 0] = ex;  cur[t * 4 + 0] = ex;  ex += h0;
    hist[t * 4 + 1] = ex;  cur[t * 4 + 1] = ex;  ex += h1;
    hist[t * 4 + 2] = ex;  cur[t * 4 + 2] = ex;  ex += h2;
    hist[t * 4 + 3] = ex;  cur[t * 4 + 3] = ex;
    __syncthreads();
    for (int b = t; b < NB; b += 256) gb2[b] -= hist[b];
    __syncthreads();

    // Phase B: sequential walk, coalesced reads, compute, stage into LDS slot.
    double smooth = 0.0;
    #pragma unroll
    for (int k = 0; k < KMAX; ++k) {
        int i = k * 256 + t;
        if (i >= Cb) break;
        int e = s + i;
        int r = (int)rr[k];
        unsigned b = (unsigned)r >> 7;
        int c = is64 ? (int)ll[(long long)E + e] : ii[E + e];
        c = min(max(c, 0), N - 1);
        float2 dxy = eattr[e];
        float4 pr = pred[r];
        float4 pc = pred[c];
        float du = pc.x - pr.x, dv = pc.y - pr.y;
        float dp = pc.z - pr.z, dn = pc.w - pr.w;
        float rx  = 1.0f / (dxy.x + EPS);
        float ry  = 1.0f / (dxy.y + EPS);
        float rx2 = 1.0f / (dxy.x * dxy.x + EPS);
        float ry2 = 1.0f / (dxy.y * dxy.y + EPS);
        float du_dx = du * rx, du_dy = du * ry;
        float dv_dx = dv * rx, dv_dy = dv * ry;
        float nu_eff = NU_MOL + pr.w;
        float div_e = du_dx + dv_dy;
        float mx_e  = dp * rx + nu_eff * du * rx2;
        float my_e  = dp * ry + nu_eff * dv * ry2;
        float sh    = du_dy + dv_dx;
        float str_e = 2.0f * (du_dx * du_dx + dv_dy * dv_dy) + sh * sh;

        unsigned pos = atomicAdd(&cur[b], 1u);
        pl[pos] = make_uint2(bf16rne(div_e) | (bf16rne(mx_e) << 16),
                             bf16rne(my_e) | (bf16rne(str_e) << 16));
        bb[pos] = (unsigned short)b;
        rls[pos] = (unsigned char)(r & (NPB - 1));

        smooth += (double)(du * du + dv * dv + dp * dp + dn * dn);
    }
    __syncthreads();

    // Phase C: sequential sweep of sorted slots -> coalesced global stores.
    #pragma unroll
    for (int k = 0; k < KMAX; ++k) {
        int p = k * 256 + t;
        if (p >= Cb) break;
        unsigned b = bb[p];
        unsigned wpos = gb2[b] + (unsigned)p;
        vals[wpos] = pl[p];
        rl8g[wpos] = rls[p];
    }

    for (int off = 32; off > 0; off >>= 1)
        smooth += __shfl_down(smooth, off);
    int lane = t & 63, wv = t >> 6;
    if (lane == 0) sm[wv] = smooth;
    __syncthreads();
    if (t == 0)
        atomicAdd(&smooth_slots[blk & 63], sm[0] + sm[1] + sm[2] + sm[3]);
}

// Pass 4: per-bucket accumulation, per-wave private LDS accumulators.
__global__ __launch_bounds__(512) void bucket_kernel(
    const uint2* __restrict__ vals, const unsigned char* __restrict__ rl8,
    const unsigned* __restrict__ base,
    const float4* __restrict__ pred, const float4* __restrict__ tgt,
    const unsigned char* __restrict__ wall, int N, double* __restrict__ d)
{
    int b = blockIdx.x;
    __shared__ float acc[8][5][NPB];
    for (int i = threadIdx.x; i < 8 * 5 * NPB; i += 512) (&acc[0][0][0])[i] = 0.0f;
    __syncthreads();

    int wv = threadIdx.x >> 6;
    unsigned s = base[b], e = base[b + 1];
    for (unsigned idx = s + threadIdx.x; idx < e; idx += 512) {
        uint2 v = vals[idx];
        unsigned rl = rl8[idx];
        atomicAdd(&acc[wv][0][rl], 1.0f);
        atomicAdd(&acc[wv][1][rl], bf16dec(v.x & 0xFFFFu));
        atomicAdd(&acc[wv][2][rl], bf16dec(v.x >> 16));
        atomicAdd(&acc[wv][3][rl], bf16dec(v.y & 0xFFFFu));
        atomicAdd(&acc[wv][4][rl], bf16dec(v.y >> 16));
    }
    __syncthreads();

    double v0 = 0, v1 = 0, v2 = 0, v3 = 0, v4 = 0, v5 = 0, v6 = 0, v7 = 0;
    int i = threadIdx.x;
    int n = b * NPB + i;
    if (i < NPB && n < N) {
        float cnt = 0, sdiv = 0, smx = 0, smy = 0, sstr = 0;
        #pragma unroll
        for (int w = 0; w < 8; ++w) {
            cnt += acc[w][0][i]; sdiv += acc[w][1][i]; smx += acc[w][2][i];
            smy += acc[w][3][i]; sstr += acc[w][4][i];
        }
        float4 p = pred[n];
        float4 t = tgt[n];
        float inv = 1.0f / fmaxf(cnt, 1.0f);
        float div = sdiv * inv;
        float mx  = smx * inv;
        float my  = smy * inv;
        float sn  = sstr * inv;
        float prod = p.w * sn;
        float m = wall[n] ? 1.0f : 0.0f;
        float e0 = p.x - t.x, e1 = p.y - t.y, e2 = p.z - t.z, e3 = p.w - t.w;
        float uv = p.x * p.x + p.y * p.y;
        v0 = (double)(e0 * e0 + e1 * e1 + e2 * e2 + e3 * e3);
        v1 = (double)div * (double)div;
        v2 = (double)mx * (double)mx + (double)my * (double)my;
        v3 = (double)prod * (double)prod;
        v4 = (double)p.w * (double)p.w;
        v5 = (double)m;
        v6 = (double)(m * uv);
        v7 = (double)(m * (uv + p.w * p.w));
    }
    for (int off = 32; off > 0; off >>= 1) {
        v0 += __shfl_down(v0, off); v1 += __shfl_down(v1, off);
        v2 += __shfl_down(v2, off); v3 += __shfl_down(v3, off);
        v4 += __shfl_down(v4, off); v5 += __shfl_down(v5, off);
        v6 += __shfl_down(v6, off); v7 += __shfl_down(v7, off);
    }
    __shared__ double sm[8][8];
    int lane = threadIdx.x & 63;
    if (lane == 0) {
        sm[wv][0] = v0; sm[wv][1] = v1; sm[wv][2] = v2; sm[wv][3] = v3;
        sm[wv][4] = v4; sm[wv][5] = v5; sm[wv][6] = v6; sm[wv][7] = v7;
    }
    __syncthreads();
    if (threadIdx.x < 8) {
        int q = threadIdx.x;
        double tsum = 0;
        #pragma unroll
        for (int w = 0; w < 8; ++w) tsum += sm[w][q];
        atomicAdd(&d[q], tsum);
    }
}

// ===================== fallback path (R1-style, known-correct) =====================

__global__ __launch_bounds__(256) void edge_kernel(
    const void* __restrict__ eidx, const float2* __restrict__ eattr,
    const float4* __restrict__ pred, int E, int N, const int* __restrict__ flag,
    float* __restrict__ a_cnt, float* __restrict__ a_div,
    float* __restrict__ a_mx, float* __restrict__ a_my,
    float* __restrict__ a_str, double* __restrict__ smooth_slots)
{
    const int is64 = *flag;
    const long long* ll = (const long long*)eidx;
    const int* ii = (const int*)eidx;
    double smooth = 0.0;
    const int stride = gridDim.x * blockDim.x;
    for (int e = blockIdx.x * blockDim.x + threadIdx.x; e < E; e += stride) {
        int row, col;
        if (is64) { row = (int)ll[e]; col = (int)ll[(long long)E + e]; }
        else      { row = ii[e];      col = ii[E + e]; }
        row = min(max(row, 0), N - 1);
        col = min(max(col, 0), N - 1);
        float2 dxy = eattr[e];
        float4 pr = pred[row];
        float4 pc = pred[col];
        float du = pc.x - pr.x, dv = pc.y - pr.y;
        float dp = pc.z - pr.z, dn = pc.w - pr.w;
        float rx  = 1.0f / (dxy.x + EPS);
        float ry  = 1.0f / (dxy.y + EPS);
        float rx2 = 1.0f / (dxy.x * dxy.x + EPS);
        float ry2 = 1.0f / (dxy.y * dxy.y + EPS);
        float du_dx = du * rx, du_dy = du * ry;
        float dv_dx = dv * rx, dv_dy = dv * ry;
        float nu_eff = NU_MOL + pr.w;
        atomicAdd(&a_cnt[row], 1.0f);
        atomicAdd(&a_div[row], du_dx + dv_dy);
        atomicAdd(&a_mx[row], dp * rx + nu_eff * du * rx2);
        atomicAdd(&a_my[row], dp * ry + nu_eff * dv * ry2);
        float sh = du_dy + dv_dx;
        atomicAdd(&a_str[row], 2.0f * (du_dx * du_dx + dv_dy * dv_dy) + sh * sh);
        smooth += (double)(du * du + dv * dv + dp * dp + dn * dn);
    }
    for (int off = 32; off > 0; off >>= 1)
        smooth += __shfl_down(smooth, off);
    __shared__ double sm[4];
    int lane = threadIdx.x & 63, wv = threadIdx.x >> 6;
    if (lane == 0) sm[wv] = smooth;
    __syncthreads();
    if (threadIdx.x == 0)
        atomicAdd(&smooth_slots[blockIdx.x & 63], sm[0] + sm[1] + sm[2] + sm[3]);
}

__global__ __launch_bounds__(256) void node_kernel(
    const float4* __restrict__ pred, const float4* __restrict__ tgt,
    const unsigned char* __restrict__ wall, int N,
    const float* __restrict__ a_cnt, const float* __restrict__ a_div,
    const float* __restrict__ a_mx, const float* __restrict__ a_my,
    const float* __restrict__ a_str, double* __restrict__ d)
{
    int i = blockIdx.x * blockDim.x + threadIdx.x;
    double v0 = 0, v1 = 0, v2 = 0, v3 = 0, v4 = 0, v5 = 0, v6 = 0, v7 = 0;
    if (i < N) {
        float4 p = pred[i];
        float4 t = tgt[i];
        float inv = 1.0f / fmaxf(a_cnt[i], 1.0f);
        float div = a_div[i] * inv;
        float mx = a_mx[i] * inv, my = a_my[i] * inv;
        float sn = a_str[i] * inv;
        float prod = p.w * sn;
        float m = wall[i] ? 1.0f : 0.0f;
        float e0 = p.x - t.x, e1 = p.y - t.y, e2 = p.z - t.z, e3 = p.w - t.w;
        float uv = p.x * p.x + p.y * p.y;
        v0 = (double)(e0 * e0 + e1 * e1 + e2 * e2 + e3 * e3);
        v1 = (double)div * (double)div;
        v2 = (double)mx * (double)mx + (double)my * (double)my;
        v3 = (double)prod * (double)prod;
        v4 = (double)p.w * (double)p.w;
        v5 = (double)m;
        v6 = (double)(m * uv);
        v7 = (double)(m * (uv + p.w * p.w));
    }
    for (int off = 32; off > 0; off >>= 1) {
        v0 += __shfl_down(v0, off); v1 += __shfl_down(v1, off);
        v2 += __shfl_down(v2, off); v3 += __shfl_down(v3, off);
        v4 += __shfl_down(v4, off); v5 += __shfl_down(v5, off);
        v6 += __shfl_down(v6, off); v7 += __shfl_down(v7, off);
    }
    __shared__ double sm[4][8];
    int lane = threadIdx.x & 63, wv = threadIdx.x >> 6;
    if (lane == 0) {
        sm[wv][0] = v0; sm[wv][1] = v1; sm[wv][2] = v2; sm[wv][3] = v3;
        sm[wv][4] = v4; sm[wv][5] = v5; sm[wv][6] = v6; sm[wv][7] = v7;
    }
    __syncthreads();
    if (threadIdx.x < 8) {
        int q = threadIdx.x;
        atomicAdd(&d[q], sm[0][q] + sm[1][q] + sm[2][q] + sm[3][q]);
    }
}

// ===================== launch =====================

extern "C" void kernel_launch(void* const* d_in, const int* in_sizes, int n_in,
                              void* d_out, int out_size, void* d_ws, size_t ws_size,
                              hipStream_t stream) {
    const float4* pred = (const float4*)d_in[0];
    const float4* tgt  = (const float4*)d_in[1];
    const float2* eattr = (const float2*)d_in[2];
    const void* eidx = d_in[3];
    const unsigned char* wall = (const unsigned char*)d_in[4];
    int N = in_sizes[0] / 4;
    int E = in_sizes[2] / 2;
    int NB = (N + NPB - 1) / NPB;
    int chunk = (E + NBLK - 1) / NBLK;

    char* ws = (char*)d_ws;
    double* d = (double*)ws;                 // 8 scalars
    double* smooth_slots = d + 8;            // 64 slots
    int* flag = (int*)(ws + 576);

    size_t off = 1024;
    unsigned* counts = (unsigned*)(ws + off); off += (size_t)NBLK * NBP * 4;
    unsigned* totals = (unsigned*)(ws + off); off += (size_t)NB * 4;
    unsigned* base   = (unsigned*)(ws + off); off += (size_t)(NB + 1) * 4;
    off = (off + 15) & ~(size_t)15;
    uint2* vals      = (uint2*)(ws + off);    off += (size_t)E * 8;
    unsigned char* rl8 = (unsigned char*)(ws + off); off += (size_t)E;
    size_t need_fast = off;

    bool fast = (NB <= MAXNB) && (chunk <= CMAX) && (ws_size >= need_fast);

    if (fast) {
        hipMemsetAsync(d_ws, 0, 1024, stream);
        detect_idx_dtype<<<1, 1, 0, stream>>>(eidx, N, flag);
        count_kernel<<<NBLK, 256, 0, stream>>>(eidx, E, N, NB, flag, counts);
        scan_tiles<<<(NB + 15) / 16, 256, 0, stream>>>(counts, totals, NB);
        scan_totals<<<1, 256, 0, stream>>>(totals, base, NB);
        sort_scatter_kernel<<<NBLK, 256, 0, stream>>>(eidx, eattr, pred, E, N, NB,
                                                      flag, counts, base, vals, rl8,
                                                      smooth_slots);
        bucket_kernel<<<NB, 512, 0, stream>>>(vals, rl8, base, pred, tgt, wall, N, d);
        finalize_kernel<<<1, 1, 0, stream>>>(d, smooth_slots, N, E, (float*)d_out);
    } else {
        float* arrays = (float*)(ws + 1024);
        float* a_cnt = arrays + (size_t)0 * N;
        float* a_div = arrays + (size_t)1 * N;
        float* a_mx  = arrays + (size_t)2 * N;
        float* a_my  = arrays + (size_t)3 * N;
        float* a_str = arrays + (size_t)4 * N;
        size_t zbytes = 1024 + (size_t)5 * N * sizeof(float);
        hipMemsetAsync(d_ws, 0, zbytes, stream);
        detect_idx_dtype<<<1, 1, 0, stream>>>(eidx, N, flag);
        edge_kernel<<<4096, 256, 0, stream>>>(eidx, eattr, pred, E, N, flag,
                                              a_cnt, a_div, a_mx, a_my, a_str,
                                              smooth_slots);
        node_kernel<<<(N + 255) / 256, 256, 0, stream>>>(pred, tgt, wall, N,
                                                         a_cnt, a_div, a_mx, a_my,
                                                         a_str, d);
        finalize_kernel<<<1, 1, 0, stream>>>(d, smooth_slots, N, E, (float*)d_out);
    }
}

// Round 6
// 369.768 us; speedup vs baseline: 6.0896x; 1.4887x over previous
//
#include <hip/hip_runtime.h>

#define EPS 1e-8f
#define NU_MOL 1.5e-5f
#define NPB 128            // nodes per bucket
#define MAXNB 832          // max buckets (N <= 106496); tables padded to 1024
#define NBP 1024           // padded row stride of counts matrix (u32 elems)
#define NBLK 2048          // edge-chunk blocks for count/scatter
#define CMAX 3328          // max edges per block chunk (E <= 6.81M)
#define KMAX 13            // CMAX / 256
#define CH 4096            // bucket_kernel chunk entries

// ===================== common =====================

__global__ void detect_idx_dtype(const void* eidx, int N, int* flag) {
    const long long* ll = (const long long*)eidx;
    int is64 = 1;
    for (int i = 0; i < 16; ++i) {
        long long v = ll[i];
        if (v < 0 || v >= (long long)N) { is64 = 0; break; }
    }
    *flag = is64;
}

__global__ void finalize_kernel(const double* __restrict__ d,
                                const double* __restrict__ smooth_slots,
                                int N, int E, float* __restrict__ out)
{
    double smooth = 0.0;
    for (int i = 0; i < 64; ++i) smooth += smooth_slots[i];
    double dN = (double)N;
    double n_wall = d[5] > 1.0 ? d[5] : 1.0;
    double total = 1.0  * d[0] / (4.0 * dN)
                 + 0.1  * d[1] / dN
                 + 0.1  * d[2] / dN
                 + 0.05 * d[3] / dN
                 + 0.05 * d[4] / dN
                 + 0.05 * d[6] / n_wall
                 + 0.01 * smooth / (4.0 * (double)E)
                 + 0.02 * d[7] / n_wall;
    out[0] = (float)total;
}

__device__ inline unsigned bf16rne(float f) {
    unsigned u = __float_as_uint(f);
    u += 0x7FFFu + ((u >> 16) & 1u);
    return u >> 16;
}
__device__ inline float bf16dec(unsigned h) {
    return __uint_as_float(h << 16);
}

// ===================== fast path =====================

// Pass 1: per-(block, bucket) edge counts. counts layout: [blk][NBP] — each
// block writes a CONTIGUOUS row.
__global__ __launch_bounds__(256) void count_kernel(
    const void* __restrict__ eidx, int E, int N, int NB,
    const int* __restrict__ flag, unsigned* __restrict__ counts)
{
    __shared__ unsigned hist[1024];
    for (int i = threadIdx.x; i < 1024; i += 256) hist[i] = 0u;
    __syncthreads();
    const int is64 = *flag;
    const long long* ll = (const long long*)eidx;
    const int* ii = (const int*)eidx;
    int chunk = (E + NBLK - 1) / NBLK;
    int s = blockIdx.x * chunk;
    int eend = min(E, s + chunk);
    for (int e = s + (int)threadIdx.x; e < eend; e += 256) {
        int r = is64 ? (int)ll[e] : ii[e];
        r = min(max(r, 0), N - 1);
        atomicAdd(&hist[r >> 7], 1u);
    }
    __syncthreads();
    for (int b = threadIdx.x; b < NB; b += 256)
        counts[(size_t)blockIdx.x * NBP + b] = hist[b];
}

// Pass 2a: per-bucket exclusive scan across blocks, tiled (coalesced rows).
__global__ __launch_bounds__(256) void scan_tiles(
    unsigned* __restrict__ counts, unsigned* __restrict__ totals, int NB)
{
    __shared__ unsigned tile[64][17];
    const int t = threadIdx.x;
    const int b0 = blockIdx.x * 16;
    const int j = t & 15;
    const int rl = t >> 4;
    const bool bok = (b0 + j) < NB;
    unsigned carry = 0;

    for (int c = 0; c < NBLK / 64; ++c) {
        #pragma unroll
        for (int s_ = 0; s_ < 4; ++s_) {
            int row = c * 64 + s_ * 16 + rl;
            tile[s_ * 16 + rl][j] = bok ? counts[(size_t)row * NBP + b0 + j] : 0u;
        }
        __syncthreads();
        if (t < 16) {
            unsigned cy = carry;
            #pragma unroll
            for (int r = 0; r < 64; ++r) {
                unsigned v = tile[r][t];
                tile[r][t] = cy;
                cy += v;
            }
            carry = cy;
        }
        __syncthreads();
        #pragma unroll
        for (int s_ = 0; s_ < 4; ++s_) {
            int row = c * 64 + s_ * 16 + rl;
            if (bok) counts[(size_t)row * NBP + b0 + j] = tile[s_ * 16 + rl][j];
        }
        __syncthreads();
    }
    if (t < 16 && bok) totals[b0 + t] = carry;
}

// Pass 2b: exclusive scan of bucket totals -> base[NB+1].
__global__ __launch_bounds__(256) void scan_totals(
    const unsigned* __restrict__ totals, unsigned* __restrict__ base, int NB)
{
    int t = threadIdx.x;
    unsigned v[4]; unsigned s = 0;
    #pragma unroll
    for (int j = 0; j < 4; ++j) {
        int i = t * 4 + j;
        v[j] = (i < NB) ? totals[i] : 0u;
        s += v[j];
    }
    __shared__ unsigned sc[256];
    sc[t] = s; __syncthreads();
    for (int off = 1; off < 256; off <<= 1) {
        unsigned x = (t >= off) ? sc[t - off] : 0u;
        __syncthreads();
        sc[t] += x;
        __syncthreads();
    }
    unsigned ex = sc[t] - s;
    #pragma unroll
    for (int j = 0; j < 4; ++j) {
        int i = t * 4 + j;
        if (i < NB) base[i] = ex;
        ex += v[j];
    }
    if (t == 255) base[NB] = sc[255];
}

// Pass 3: rows -> registers; sequential compute; LDS-staged permutation;
// coalesced bf16x4 payload stores.
__global__ __launch_bounds__(256) void sort_scatter_kernel(
    const void* __restrict__ eidx, const float2* __restrict__ eattr,
    const float4* __restrict__ pred, int E, int N, int NB,
    const int* __restrict__ flag,
    const unsigned* __restrict__ localoff, const unsigned* __restrict__ base,
    uint2* __restrict__ vals, unsigned char* __restrict__ rl8g,
    double* __restrict__ smooth_slots)
{
    __shared__ unsigned hist[1024];
    __shared__ unsigned cur[1024];
    __shared__ unsigned gb2[1024];
    __shared__ uint2 pl[CMAX];
    __shared__ unsigned short bb[CMAX];
    __shared__ unsigned char rls[CMAX];
    __shared__ unsigned sc[256];
    __shared__ double sm[4];

    const int t = threadIdx.x;
    const int blk = blockIdx.x;
    const int is64 = *flag;
    const long long* ll = (const long long*)eidx;
    const int* ii = (const int*)eidx;
    const int chunk = (E + NBLK - 1) / NBLK;
    const int s = blk * chunk;
    const int Cb = min(chunk, E - s);

    for (int i = t; i < 1024; i += 256) hist[i] = 0u;
    __syncthreads();

    unsigned rr[KMAX];
    #pragma unroll
    for (int k = 0; k < KMAX; ++k) {
        int i = k * 256 + t;
        if (i < Cb) {
            int r = is64 ? (int)ll[s + i] : ii[s + i];
            r = min(max(r, 0), N - 1);
            rr[k] = (unsigned)r;
            atomicAdd(&hist[r >> 7], 1u);
        } else rr[k] = 0xFFFFFFFFu;
    }
    for (int b = t; b < NB; b += 256)
        gb2[b] = base[b] + localoff[(size_t)blk * NBP + b];
    __syncthreads();

    unsigned h0 = hist[t * 4 + 0], h1 = hist[t * 4 + 1];
    unsigned h2 = hist[t * 4 + 2], h3 = hist[t * 4 + 3];
    unsigned psum = h0 + h1 + h2 + h3;
    sc[t] = psum; __syncthreads();
    for (int off = 1; off < 256; off <<= 1) {
        unsigned x = (t >= off) ? sc[t - off] : 0u;
        __syncthreads();
        sc[t] += x;
        __syncthreads();
    }
    unsigned ex = sc[t] - psum;
    hist[t * 4 + 0] = ex;  cur[t * 4 + 0] = ex;  ex += h0;
    hist[t * 4 + 1] = ex;  cur[t * 4 + 1] = ex;  ex += h1;
    hist[t * 4 + 2] = ex;  cur[t * 4 + 2] = ex;  ex += h2;
    hist[t * 4 + 3] = ex;  cur[t * 4 + 3] = ex;
    __syncthreads();
    for (int b = t; b < NB; b += 256) gb2[b] -= hist[b];
    __syncthreads();

    double smooth = 0.0;
    #pragma unroll
    for (int k = 0; k < KMAX; ++k) {
        int i = k * 256 + t;
        if (i >= Cb) break;
        int e = s + i;
        int r = (int)rr[k];
        unsigned b = (unsigned)r >> 7;
        int c = is64 ? (int)ll[(long long)E + e] : ii[E + e];
        c = min(max(c, 0), N - 1);
        float2 dxy = eattr[e];
        float4 pr = pred[r];
        float4 pc = pred[c];
        float du = pc.x - pr.x, dv = pc.y - pr.y;
        float dp = pc.z - pr.z, dn = pc.w - pr.w;
        float rx  = 1.0f / (dxy.x + EPS);
        float ry  = 1.0f / (dxy.y + EPS);
        float rx2 = 1.0f / (dxy.x * dxy.x + EPS);
        float ry2 = 1.0f / (dxy.y * dxy.y + EPS);
        float du_dx = du * rx, du_dy = du * ry;
        float dv_dx = dv * rx, dv_dy = dv * ry;
        float nu_eff = NU_MOL + pr.w;
        float div_e = du_dx + dv_dy;
        float mx_e  = dp * rx + nu_eff * du * rx2;
        float my_e  = dp * ry + nu_eff * dv * ry2;
        float sh    = du_dy + dv_dx;
        float str_e = 2.0f * (du_dx * du_dx + dv_dy * dv_dy) + sh * sh;

        unsigned pos = atomicAdd(&cur[b], 1u);
        pl[pos] = make_uint2(bf16rne(div_e) | (bf16rne(mx_e) << 16),
                             bf16rne(my_e) | (bf16rne(str_e) << 16));
        bb[pos] = (unsigned short)b;
        rls[pos] = (unsigned char)(r & (NPB - 1));

        smooth += (double)(du * du + dv * dv + dp * dp + dn * dn);
    }
    __syncthreads();

    #pragma unroll
    for (int k = 0; k < KMAX; ++k) {
        int p = k * 256 + t;
        if (p >= Cb) break;
        unsigned b = bb[p];
        unsigned wpos = gb2[b] + (unsigned)p;
        vals[wpos] = pl[p];
        rl8g[wpos] = rls[p];
    }

    for (int off = 32; off > 0; off >>= 1)
        smooth += __shfl_down(smooth, off);
    int lane = t & 63, wv = t >> 6;
    if (lane == 0) sm[wv] = smooth;
    __syncthreads();
    if (t == 0)
        atomicAdd(&smooth_slots[blk & 63], sm[0] + sm[1] + sm[2] + sm[3]);
}

// Pass 4: chunked LDS counting-sort + register run-sum. No accumulation
// atomics: histogram gives counts; sorted runs are summed sequentially.
__global__ __launch_bounds__(256) void bucket_kernel(
    const uint2* __restrict__ vals, const unsigned char* __restrict__ rl8,
    const unsigned* __restrict__ base,
    const float4* __restrict__ pred, const float4* __restrict__ tgt,
    const unsigned char* __restrict__ wall, int N, double* __restrict__ d)
{
    __shared__ uint2 pl[CH];               // 32 KB sorted payload
    __shared__ unsigned char rls[CH];      // 4 KB
    __shared__ unsigned hist[NPB];
    __shared__ unsigned cur[NPB];
    __shared__ unsigned wsum;
    __shared__ double sm[4][8];

    const int b = blockIdx.x;
    const int t = threadIdx.x;
    const unsigned s = base[b], e = base[b + 1];

    float cnt = 0, sdiv = 0, smx = 0, smy = 0, sstr = 0;  // node accumulators (t<128)

    for (unsigned cs = s; cs < e; cs += CH) {
        const int n = (int)min((unsigned)CH, e - cs);
        if (t < NPB) hist[t] = 0u;
        __syncthreads();

        // stage rl + histogram (coalesced u8 reads)
        for (int i = t; i < n; i += 256) {
            unsigned char r = rl8[cs + i];
            rls[i] = r;
            atomicAdd(&hist[r], 1u);
        }
        __syncthreads();

        // exclusive scan of 128 bins via wave shuffles
        unsigned v = 0, x = 0;
        if (t < NPB) { v = hist[t]; x = v; }
        #pragma unroll
        for (int off = 1; off < 64; off <<= 1) {
            unsigned y = (unsigned)__shfl_up((int)x, off, 64);
            if ((t & 63) >= off) x += y;
        }
        if (t == 63) wsum = x;
        __syncthreads();
        unsigned incl = 0, ex0 = 0;
        if (t < NPB) {
            incl = x + ((t >= 64) ? wsum : 0u);
            ex0 = incl - v;
            cur[t] = ex0;
            cnt += (float)v;               // count from histogram — no atomic
        }
        __syncthreads();

        // scatter payload into sorted LDS slots (coalesced global read)
        for (int i = t; i < n; i += 256) {
            unsigned r = rls[i];
            unsigned pos = atomicAdd(&cur[r], 1u);
            pl[pos] = vals[cs + i];
        }
        __syncthreads();

        // register run-sum over contiguous run [ex0, incl)
        if (t < NPB) {
            for (unsigned i = ex0; i < incl; ++i) {
                uint2 pv = pl[i];
                sdiv += bf16dec(pv.x & 0xFFFFu);
                smx  += bf16dec(pv.x >> 16);
                smy  += bf16dec(pv.y & 0xFFFFu);
                sstr += bf16dec(pv.y >> 16);
            }
        }
        __syncthreads();
    }

    // fused node losses
    double v0 = 0, v1 = 0, v2 = 0, v3 = 0, v4 = 0, v5 = 0, v6 = 0, v7 = 0;
    int n_ = b * NPB + t;
    if (t < NPB && n_ < N) {
        float4 p = pred[n_];
        float4 tg = tgt[n_];
        float inv = 1.0f / fmaxf(cnt, 1.0f);
        float div = sdiv * inv;
        float mx  = smx * inv;
        float my  = smy * inv;
        float sn  = sstr * inv;
        float prod = p.w * sn;
        float m = wall[n_] ? 1.0f : 0.0f;
        float e0 = p.x - tg.x, e1 = p.y - tg.y, e2 = p.z - tg.z, e3 = p.w - tg.w;
        float uv = p.x * p.x + p.y * p.y;
        v0 = (double)(e0 * e0 + e1 * e1 + e2 * e2 + e3 * e3);
        v1 = (double)div * (double)div;
        v2 = (double)mx * (double)mx + (double)my * (double)my;
        v3 = (double)prod * (double)prod;
        v4 = (double)p.w * (double)p.w;
        v5 = (double)m;
        v6 = (double)(m * uv);
        v7 = (double)(m * (uv + p.w * p.w));
    }
    for (int off = 32; off > 0; off >>= 1) {
        v0 += __shfl_down(v0, off); v1 += __shfl_down(v1, off);
        v2 += __shfl_down(v2, off); v3 += __shfl_down(v3, off);
        v4 += __shfl_down(v4, off); v5 += __shfl_down(v5, off);
        v6 += __shfl_down(v6, off); v7 += __shfl_down(v7, off);
    }
    int lane = t & 63, wv = t >> 6;
    if (lane == 0) {
        sm[wv][0] = v0; sm[wv][1] = v1; sm[wv][2] = v2; sm[wv][3] = v3;
        sm[wv][4] = v4; sm[wv][5] = v5; sm[wv][6] = v6; sm[wv][7] = v7;
    }
    __syncthreads();
    if (t < 8) {
        double tsum = sm[0][t] + sm[1][t] + sm[2][t] + sm[3][t];
        atomicAdd(&d[t], tsum);
    }
}

// ===================== fallback path (R1-style, known-correct) =====================

__global__ __launch_bounds__(256) void edge_kernel(
    const void* __restrict__ eidx, const float2* __restrict__ eattr,
    const float4* __restrict__ pred, int E, int N, const int* __restrict__ flag,
    float* __restrict__ a_cnt, float* __restrict__ a_div,
    float* __restrict__ a_mx, float* __restrict__ a_my,
    float* __restrict__ a_str, double* __restrict__ smooth_slots)
{
    const int is64 = *flag;
    const long long* ll = (const long long*)eidx;
    const int* ii = (const int*)eidx;
    double smooth = 0.0;
    const int stride = gridDim.x * blockDim.x;
    for (int e = blockIdx.x * blockDim.x + threadIdx.x; e < E; e += stride) {
        int row, col;
        if (is64) { row = (int)ll[e]; col = (int)ll[(long long)E + e]; }
        else      { row = ii[e];      col = ii[E + e]; }
        row = min(max(row, 0), N - 1);
        col = min(max(col, 0), N - 1);
        float2 dxy = eattr[e];
        float4 pr = pred[row];
        float4 pc = pred[col];
        float du = pc.x - pr.x, dv = pc.y - pr.y;
        float dp = pc.z - pr.z, dn = pc.w - pr.w;
        float rx  = 1.0f / (dxy.x + EPS);
        float ry  = 1.0f / (dxy.y + EPS);
        float rx2 = 1.0f / (dxy.x * dxy.x + EPS);
        float ry2 = 1.0f / (dxy.y * dxy.y + EPS);
        float du_dx = du * rx, du_dy = du * ry;
        float dv_dx = dv * rx, dv_dy = dv * ry;
        float nu_eff = NU_MOL + pr.w;
        atomicAdd(&a_cnt[row], 1.0f);
        atomicAdd(&a_div[row], du_dx + dv_dy);
        atomicAdd(&a_mx[row], dp * rx + nu_eff * du * rx2);
        atomicAdd(&a_my[row], dp * ry + nu_eff * dv * ry2);
        float sh = du_dy + dv_dx;
        atomicAdd(&a_str[row], 2.0f * (du_dx * du_dx + dv_dy * dv_dy) + sh * sh);
        smooth += (double)(du * du + dv * dv + dp * dp + dn * dn);
    }
    for (int off = 32; off > 0; off >>= 1)
        smooth += __shfl_down(smooth, off);
    __shared__ double sm[4];
    int lane = threadIdx.x & 63, wv = threadIdx.x >> 6;
    if (lane == 0) sm[wv] = smooth;
    __syncthreads();
    if (threadIdx.x == 0)
        atomicAdd(&smooth_slots[blockIdx.x & 63], sm[0] + sm[1] + sm[2] + sm[3]);
}

__global__ __launch_bounds__(256) void node_kernel(
    const float4* __restrict__ pred, const float4* __restrict__ tgt,
    const unsigned char* __restrict__ wall, int N,
    const float* __restrict__ a_cnt, const float* __restrict__ a_div,
    const float* __restrict__ a_mx, const float* __restrict__ a_my,
    const float* __restrict__ a_str, double* __restrict__ d)
{
    int i = blockIdx.x * blockDim.x + threadIdx.x;
    double v0 = 0, v1 = 0, v2 = 0, v3 = 0, v4 = 0, v5 = 0, v6 = 0, v7 = 0;
    if (i < N) {
        float4 p = pred[i];
        float4 t = tgt[i];
        float inv = 1.0f / fmaxf(a_cnt[i], 1.0f);
        float div = a_div[i] * inv;
        float mx = a_mx[i] * inv, my = a_my[i] * inv;
        float sn = a_str[i] * inv;
        float prod = p.w * sn;
        float m = wall[i] ? 1.0f : 0.0f;
        float e0 = p.x - t.x, e1 = p.y - t.y, e2 = p.z - t.z, e3 = p.w - t.w;
        float uv = p.x * p.x + p.y * p.y;
        v0 = (double)(e0 * e0 + e1 * e1 + e2 * e2 + e3 * e3);
        v1 = (double)div * (double)div;
        v2 = (double)mx * (double)mx + (double)my * (double)my;
        v3 = (double)prod * (double)prod;
        v4 = (double)p.w * (double)p.w;
        v5 = (double)m;
        v6 = (double)(m * uv);
        v7 = (double)(m * (uv + p.w * p.w));
    }
    for (int off = 32; off > 0; off >>= 1) {
        v0 += __shfl_down(v0, off); v1 += __shfl_down(v1, off);
        v2 += __shfl_down(v2, off); v3 += __shfl_down(v3, off);
        v4 += __shfl_down(v4, off); v5 += __shfl_down(v5, off);
        v6 += __shfl_down(v6, off); v7 += __shfl_down(v7, off);
    }
    __shared__ double sm[4][8];
    int lane = threadIdx.x & 63, wv = threadIdx.x >> 6;
    if (lane == 0) {
        sm[wv][0] = v0; sm[wv][1] = v1; sm[wv][2] = v2; sm[wv][3] = v3;
        sm[wv][4] = v4; sm[wv][5] = v5; sm[wv][6] = v6; sm[wv][7] = v7;
    }
    __syncthreads();
    if (threadIdx.x < 8) {
        int q = threadIdx.x;
        atomicAdd(&d[q], sm[0][q] + sm[1][q] + sm[2][q] + sm[3][q]);
    }
}

// ===================== launch =====================

extern "C" void kernel_launch(void* const* d_in, const int* in_sizes, int n_in,
                              void* d_out, int out_size, void* d_ws, size_t ws_size,
                              hipStream_t stream) {
    const float4* pred = (const float4*)d_in[0];
    const float4* tgt  = (const float4*)d_in[1];
    const float2* eattr = (const float2*)d_in[2];
    const void* eidx = d_in[3];
    const unsigned char* wall = (const unsigned char*)d_in[4];
    int N = in_sizes[0] / 4;
    int E = in_sizes[2] / 2;
    int NB = (N + NPB - 1) / NPB;
    int chunk = (E + NBLK - 1) / NBLK;

    char* ws = (char*)d_ws;
    double* d = (double*)ws;                 // 8 scalars
    double* smooth_slots = d + 8;            // 64 slots
    int* flag = (int*)(ws + 576);

    size_t off = 1024;
    unsigned* counts = (unsigned*)(ws + off); off += (size_t)NBLK * NBP * 4;
    unsigned* totals = (unsigned*)(ws + off); off += (size_t)NB * 4;
    unsigned* base   = (unsigned*)(ws + off); off += (size_t)(NB + 1) * 4;
    off = (off + 15) & ~(size_t)15;
    uint2* vals      = (uint2*)(ws + off);    off += (size_t)E * 8;
    unsigned char* rl8 = (unsigned char*)(ws + off); off += (size_t)E;
    size_t need_fast = off;

    bool fast = (NB <= MAXNB) && (chunk <= CMAX) && (ws_size >= need_fast);

    if (fast) {
        hipMemsetAsync(d_ws, 0, 1024, stream);
        detect_idx_dtype<<<1, 1, 0, stream>>>(eidx, N, flag);
        count_kernel<<<NBLK, 256, 0, stream>>>(eidx, E, N, NB, flag, counts);
        scan_tiles<<<(NB + 15) / 16, 256, 0, stream>>>(counts, totals, NB);
        scan_totals<<<1, 256, 0, stream>>>(totals, base, NB);
        sort_scatter_kernel<<<NBLK, 256, 0, stream>>>(eidx, eattr, pred, E, N, NB,
                                                      flag, counts, base, vals, rl8,
                                                      smooth_slots);
        bucket_kernel<<<NB, 256, 0, stream>>>(vals, rl8, base, pred, tgt, wall, N, d);
        finalize_kernel<<<1, 1, 0, stream>>>(d, smooth_slots, N, E, (float*)d_out);
    } else {
        float* arrays = (float*)(ws + 1024);
        float* a_cnt = arrays + (size_t)0 * N;
        float* a_div = arrays + (size_t)1 * N;
        float* a_mx  = arrays + (size_t)2 * N;
        float* a_my  = arrays + (size_t)3 * N;
        float* a_str = arrays + (size_t)4 * N;
        size_t zbytes = 1024 + (size_t)5 * N * sizeof(float);
        hipMemsetAsync(d_ws, 0, zbytes, stream);
        detect_idx_dtype<<<1, 1, 0, stream>>>(eidx, N, flag);
        edge_kernel<<<4096, 256, 0, stream>>>(eidx, eattr, pred, E, N, flag,
                                              a_cnt, a_div, a_mx, a_my, a_str,
                                              smooth_slots);
        node_kernel<<<(N + 255) / 256, 256, 0, stream>>>(pred, tgt, wall, N,
                                                         a_cnt, a_div, a_mx, a_my,
                                                         a_str, d);
        finalize_kernel<<<1, 1, 0, stream>>>(d, smooth_slots, N, E, (float*)d_out);
    }
}

// Round 7
// 341.790 us; speedup vs baseline: 6.5880x; 1.0819x over previous
//
#include <hip/hip_runtime.h>

#define EPS 1e-8f
#define NU_MOL 1.5e-5f
#define NPB 256            // nodes per bucket
#define MAXNB 512          // max buckets (N <= 131072)
#define NBP 512            // padded row stride of counts matrix (u32 elems)
#define NBLK 4096          // edge-chunk blocks for count/scatter
#define CMAX 1664          // max edges per block chunk (E <= 6.81M)
#define KMAX 7             // ceil(CMAX / 256)
#define CH 4096            // bucket_kernel chunk entries
#define NGRP 64            // block-groups for hierarchical scan
#define GRP 64             // rows (blocks) per group; NGRP*GRP == NBLK

// ===================== common =====================

__global__ void detect_idx_dtype(const void* eidx, int N, int* flag) {
    const long long* ll = (const long long*)eidx;
    int is64 = 1;
    for (int i = 0; i < 16; ++i) {
        long long v = ll[i];
        if (v < 0 || v >= (long long)N) { is64 = 0; break; }
    }
    *flag = is64;
}

__global__ void finalize_kernel(const double* __restrict__ d,
                                const double* __restrict__ smooth_slots,
                                int N, int E, float* __restrict__ out)
{
    double smooth = 0.0;
    for (int i = 0; i < 64; ++i) smooth += smooth_slots[i];
    double dN = (double)N;
    double n_wall = d[5] > 1.0 ? d[5] : 1.0;
    double total = 1.0  * d[0] / (4.0 * dN)
                 + 0.1  * d[1] / dN
                 + 0.1  * d[2] / dN
                 + 0.05 * d[3] / dN
                 + 0.05 * d[4] / dN
                 + 0.05 * d[6] / n_wall
                 + 0.01 * smooth / (4.0 * (double)E)
                 + 0.02 * d[7] / n_wall;
    out[0] = (float)total;
}

__device__ inline unsigned bf16rne(float f) {
    unsigned u = __float_as_uint(f);
    u += 0x7FFFu + ((u >> 16) & 1u);
    return u >> 16;
}
__device__ inline float bf16dec(unsigned h) {
    return __uint_as_float(h << 16);
}

// ===================== fast path =====================

// Pass 1: per-(block, bucket) counts; each block writes a contiguous row.
__global__ __launch_bounds__(256) void count_kernel(
    const void* __restrict__ eidx, int E, int N, int NB,
    const int* __restrict__ flag, unsigned* __restrict__ counts)
{
    __shared__ unsigned hist[MAXNB];
    for (int i = threadIdx.x; i < MAXNB; i += 256) hist[i] = 0u;
    __syncthreads();
    const int is64 = *flag;
    const long long* ll = (const long long*)eidx;
    const int* ii = (const int*)eidx;
    int chunk = (E + NBLK - 1) / NBLK;
    int s = blockIdx.x * chunk;
    int eend = min(E, s + chunk);
    for (int e = s + (int)threadIdx.x; e < eend; e += 256) {
        int r = is64 ? (int)ll[e] : ii[e];
        r = min(max(r, 0), N - 1);
        atomicAdd(&hist[r >> 8], 1u);
    }
    __syncthreads();
    for (int b = threadIdx.x; b < NB; b += 256)
        counts[(size_t)blockIdx.x * NBP + b] = hist[b];
}

// Pass 2a: per-(group, bucket) sums of 64 block-rows. Fully parallel.
__global__ __launch_bounds__(256) void group_sums_kernel(
    const unsigned* __restrict__ counts, unsigned* __restrict__ gsum, int NB)
{
    __shared__ unsigned red[4][64];
    int g = blockIdx.x;
    int b0 = blockIdx.y * 64;
    int j = threadIdx.x & 63, seg = threadIdx.x >> 6;
    int b = b0 + j;
    unsigned ssum = 0;
    if (b < NB) {
        #pragma unroll
        for (int k = 0; k < 16; ++k) {
            int row = g * GRP + seg * 16 + k;
            ssum += counts[(size_t)row * NBP + b];
        }
    }
    red[seg][j] = ssum;
    __syncthreads();
    if (seg == 0 && b < NB)
        gsum[(size_t)g * NBP + b] = red[0][j] + red[1][j] + red[2][j] + red[3][j];
}

// Pass 2b: per-bucket scan over groups + bucket-totals scan -> base.
// Folds base[b] into gsum so gsum[g][b] = global exclusive offset of group g.
__global__ __launch_bounds__(512) void scan_base_kernel(
    unsigned* __restrict__ gsum, unsigned* __restrict__ base, int NB)
{
    __shared__ unsigned sc[512];
    int t = threadIdx.x;
    unsigned total = 0;
    if (t < NB)
        for (int g = 0; g < NGRP; ++g) total += gsum[(size_t)g * NBP + t];
    sc[t] = total; __syncthreads();
    for (int off = 1; off < 512; off <<= 1) {
        unsigned x = (t >= off) ? sc[t - off] : 0u;
        __syncthreads();
        sc[t] += x;
        __syncthreads();
    }
    unsigned ex = sc[t] - total;
    if (t < NB) {
        base[t] = ex;
        unsigned run = ex;
        for (int g = 0; g < NGRP; ++g) {
            unsigned x = gsum[(size_t)g * NBP + t];
            gsum[(size_t)g * NBP + t] = run;
            run += x;
        }
    }
    if (t == 511) base[NB] = sc[511];
}

// Pass 2c: within-group scan; counts[blk][b] becomes the final global
// exclusive write offset for (blk, b). Fully parallel, coalesced.
__global__ __launch_bounds__(256) void local_scan_kernel(
    unsigned* __restrict__ counts, const unsigned* __restrict__ gsum, int NB)
{
    __shared__ unsigned segs[4][64];
    int g = blockIdx.x;
    int b0 = blockIdx.y * 64;
    int j = threadIdx.x & 63, seg = threadIdx.x >> 6;
    int b = b0 + j;
    unsigned v[16];
    unsigned ssum = 0;
    if (b < NB) {
        #pragma unroll
        for (int k = 0; k < 16; ++k) {
            int row = g * GRP + seg * 16 + k;
            v[k] = counts[(size_t)row * NBP + b];
            ssum += v[k];
        }
    }
    segs[seg][j] = ssum;
    __syncthreads();
    if (b < NB) {
        unsigned carry = gsum[(size_t)g * NBP + b];
        for (int s_ = 0; s_ < seg; ++s_) carry += segs[s_][j];
        #pragma unroll
        for (int k = 0; k < 16; ++k) {
            int row = g * GRP + seg * 16 + k;
            counts[(size_t)row * NBP + b] = carry;
            carry += v[k];
        }
    }
}

// Pass 3: lean-LDS sort-scatter (~25.5 KB -> 6 blocks/CU).
__global__ __launch_bounds__(256) void sort_scatter_kernel(
    const void* __restrict__ eidx, const float2* __restrict__ eattr,
    const float4* __restrict__ pred, int E, int N, int NB,
    const int* __restrict__ flag,
    const unsigned* __restrict__ localoff /* scanned counts [blk][NBP] */,
    uint2* __restrict__ vals, unsigned char* __restrict__ rl8g,
    double* __restrict__ smooth_slots)
{
    __shared__ unsigned hist[MAXNB];
    __shared__ unsigned cur[MAXNB];
    __shared__ unsigned gb2[MAXNB];
    __shared__ uint2 pl[CMAX];
    __shared__ unsigned short bb[CMAX];
    __shared__ unsigned char rls[CMAX];
    __shared__ unsigned sc[256];
    __shared__ double sm[4];

    const int t = threadIdx.x;
    const int blk = blockIdx.x;
    const int is64 = *flag;
    const long long* ll = (const long long*)eidx;
    const int* ii = (const int*)eidx;
    const int chunk = (E + NBLK - 1) / NBLK;
    const int s = blk * chunk;
    const int Cb = min(chunk, E - s);

    hist[2 * t] = 0u; hist[2 * t + 1] = 0u;
    __syncthreads();

    unsigned rr[KMAX];
    #pragma unroll
    for (int k = 0; k < KMAX; ++k) {
        int i = k * 256 + t;
        if (i < Cb) {
            int r = is64 ? (int)ll[s + i] : ii[s + i];
            r = min(max(r, 0), N - 1);
            rr[k] = (unsigned)r;
            atomicAdd(&hist[r >> 8], 1u);
        } else rr[k] = 0xFFFFFFFFu;
    }
    for (int b = t; b < NB; b += 256)
        gb2[b] = localoff[(size_t)blk * NBP + b];
    __syncthreads();

    // exclusive scan of hist[0..511] (2 per thread) -> scan0
    unsigned h0 = hist[2 * t], h1 = hist[2 * t + 1];
    unsigned psum = h0 + h1;
    sc[t] = psum; __syncthreads();
    for (int off = 1; off < 256; off <<= 1) {
        unsigned x = (t >= off) ? sc[t - off] : 0u;
        __syncthreads();
        sc[t] += x;
        __syncthreads();
    }
    unsigned ex = sc[t] - psum;
    hist[2 * t] = ex;     cur[2 * t] = ex;     ex += h0;
    hist[2 * t + 1] = ex; cur[2 * t + 1] = ex;
    __syncthreads();
    for (int b = t; b < NB; b += 256) gb2[b] -= hist[b];
    __syncthreads();

    // Phase B: sequential coalesced compute, stage into sorted LDS slot.
    double smooth = 0.0;
    #pragma unroll
    for (int k = 0; k < KMAX; ++k) {
        int i = k * 256 + t;
        if (i >= Cb) break;
        int e = s + i;
        int r = (int)rr[k];
        unsigned b = (unsigned)r >> 8;
        int c = is64 ? (int)ll[(long long)E + e] : ii[E + e];
        c = min(max(c, 0), N - 1);
        float2 dxy = eattr[e];
        float4 pr = pred[r];
        float4 pc = pred[c];
        float du = pc.x - pr.x, dv = pc.y - pr.y;
        float dp = pc.z - pr.z, dn = pc.w - pr.w;
        float rx  = 1.0f / (dxy.x + EPS);
        float ry  = 1.0f / (dxy.y + EPS);
        float rx2 = 1.0f / (dxy.x * dxy.x + EPS);
        float ry2 = 1.0f / (dxy.y * dxy.y + EPS);
        float du_dx = du * rx, du_dy = du * ry;
        float dv_dx = dv * rx, dv_dy = dv * ry;
        float nu_eff = NU_MOL + pr.w;
        float div_e = du_dx + dv_dy;
        float mx_e  = dp * rx + nu_eff * du * rx2;
        float my_e  = dp * ry + nu_eff * dv * ry2;
        float sh    = du_dy + dv_dx;
        float str_e = 2.0f * (du_dx * du_dx + dv_dy * dv_dy) + sh * sh;

        unsigned pos = atomicAdd(&cur[b], 1u);
        pl[pos] = make_uint2(bf16rne(div_e) | (bf16rne(mx_e) << 16),
                             bf16rne(my_e) | (bf16rne(str_e) << 16));
        bb[pos] = (unsigned short)b;
        rls[pos] = (unsigned char)(r & (NPB - 1));

        smooth += (double)(du * du + dv * dv + dp * dp + dn * dn);
    }
    __syncthreads();

    // Phase C: coalesced global stores of sorted slots.
    #pragma unroll
    for (int k = 0; k < KMAX; ++k) {
        int p = k * 256 + t;
        if (p >= Cb) break;
        unsigned b = bb[p];
        unsigned wpos = gb2[b] + (unsigned)p;
        vals[wpos] = pl[p];
        rl8g[wpos] = rls[p];
    }

    for (int off = 32; off > 0; off >>= 1)
        smooth += __shfl_down(smooth, off);
    int lane = t & 63, wv = t >> 6;
    if (lane == 0) sm[wv] = smooth;
    __syncthreads();
    if (t == 0)
        atomicAdd(&smooth_slots[blk & 63], sm[0] + sm[1] + sm[2] + sm[3]);
}

// Pass 4: chunked LDS counting-sort + register run-sum; 1 node/thread.
__global__ __launch_bounds__(256) void bucket_kernel(
    const uint2* __restrict__ vals, const unsigned char* __restrict__ rl8,
    const unsigned* __restrict__ base,
    const float4* __restrict__ pred, const float4* __restrict__ tgt,
    const unsigned char* __restrict__ wall, int N, double* __restrict__ d)
{
    __shared__ uint2 pl[CH];               // 32 KB
    __shared__ unsigned char rls[CH];      // 4 KB
    __shared__ unsigned hist[NPB];
    __shared__ unsigned cur[NPB];
    __shared__ unsigned wt[4];
    __shared__ double sm[4][8];

    const int b = blockIdx.x;
    const int t = threadIdx.x;
    const unsigned s = base[b], e = base[b + 1];

    float cnt = 0, sdiv = 0, smx = 0, smy = 0, sstr = 0;

    for (unsigned cs = s; cs < e; cs += CH) {
        const int n = (int)min((unsigned)CH, e - cs);
        hist[t] = 0u;
        __syncthreads();

        for (int i = t; i < n; i += 256) {
            unsigned char r = rl8[cs + i];
            rls[i] = r;
            atomicAdd(&hist[r], 1u);
        }
        __syncthreads();

        // exclusive scan of 256 bins: intra-wave shfl + cross-wave combine
        unsigned v = hist[t];
        unsigned x = v;
        #pragma unroll
        for (int off = 1; off < 64; off <<= 1) {
            unsigned y = (unsigned)__shfl_up((int)x, off, 64);
            if ((t & 63) >= off) x += y;
        }
        if ((t & 63) == 63) wt[t >> 6] = x;
        __syncthreads();
        unsigned wadd = 0;
        for (int w = 0; w < (t >> 6); ++w) wadd += wt[w];
        unsigned incl = x + wadd;
        unsigned ex0 = incl - v;
        cur[t] = ex0;
        cnt += (float)v;
        __syncthreads();

        for (int i = t; i < n; i += 256) {
            unsigned pos = atomicAdd(&cur[rls[i]], 1u);
            pl[pos] = vals[cs + i];
        }
        __syncthreads();

        for (unsigned i = ex0; i < incl; ++i) {
            uint2 pv = pl[i];
            sdiv += bf16dec(pv.x & 0xFFFFu);
            smx  += bf16dec(pv.x >> 16);
            smy  += bf16dec(pv.y & 0xFFFFu);
            sstr += bf16dec(pv.y >> 16);
        }
        __syncthreads();
    }

    // fused node losses (node n_ owned by thread t)
    double v0 = 0, v1 = 0, v2 = 0, v3 = 0, v4 = 0, v5 = 0, v6 = 0, v7 = 0;
    int n_ = b * NPB + t;
    if (n_ < N) {
        float4 p = pred[n_];
        float4 tg = tgt[n_];
        float inv = 1.0f / fmaxf(cnt, 1.0f);
        float div = sdiv * inv;
        float mx  = smx * inv;
        float my  = smy * inv;
        float sn  = sstr * inv;
        float prod = p.w * sn;
        float m = wall[n_] ? 1.0f : 0.0f;
        float e0 = p.x - tg.x, e1 = p.y - tg.y, e2 = p.z - tg.z, e3 = p.w - tg.w;
        float uv = p.x * p.x + p.y * p.y;
        v0 = (double)(e0 * e0 + e1 * e1 + e2 * e2 + e3 * e3);
        v1 = (double)div * (double)div;
        v2 = (double)mx * (double)mx + (double)my * (double)my;
        v3 = (double)prod * (double)prod;
        v4 = (double)p.w * (double)p.w;
        v5 = (double)m;
        v6 = (double)(m * uv);
        v7 = (double)(m * (uv + p.w * p.w));
    }
    for (int off = 32; off > 0; off >>= 1) {
        v0 += __shfl_down(v0, off); v1 += __shfl_down(v1, off);
        v2 += __shfl_down(v2, off); v3 += __shfl_down(v3, off);
        v4 += __shfl_down(v4, off); v5 += __shfl_down(v5, off);
        v6 += __shfl_down(v6, off); v7 += __shfl_down(v7, off);
    }
    int lane = t & 63, wv = t >> 6;
    if (lane == 0) {
        sm[wv][0] = v0; sm[wv][1] = v1; sm[wv][2] = v2; sm[wv][3] = v3;
        sm[wv][4] = v4; sm[wv][5] = v5; sm[wv][6] = v6; sm[wv][7] = v7;
    }
    __syncthreads();
    if (t < 8) {
        double tsum = sm[0][t] + sm[1][t] + sm[2][t] + sm[3][t];
        atomicAdd(&d[t], tsum);
    }
}

// ===================== fallback path (R1-style, known-correct) =====================

__global__ __launch_bounds__(256) void edge_kernel(
    const void* __restrict__ eidx, const float2* __restrict__ eattr,
    const float4* __restrict__ pred, int E, int N, const int* __restrict__ flag,
    float* __restrict__ a_cnt, float* __restrict__ a_div,
    float* __restrict__ a_mx, float* __restrict__ a_my,
    float* __restrict__ a_str, double* __restrict__ smooth_slots)
{
    const int is64 = *flag;
    const long long* ll = (const long long*)eidx;
    const int* ii = (const int*)eidx;
    double smooth = 0.0;
    const int stride = gridDim.x * blockDim.x;
    for (int e = blockIdx.x * blockDim.x + threadIdx.x; e < E; e += stride) {
        int row, col;
        if (is64) { row = (int)ll[e]; col = (int)ll[(long long)E + e]; }
        else      { row = ii[e];      col = ii[E + e]; }
        row = min(max(row, 0), N - 1);
        col = min(max(col, 0), N - 1);
        float2 dxy = eattr[e];
        float4 pr = pred[row];
        float4 pc = pred[col];
        float du = pc.x - pr.x, dv = pc.y - pr.y;
        float dp = pc.z - pr.z, dn = pc.w - pr.w;
        float rx  = 1.0f / (dxy.x + EPS);
        float ry  = 1.0f / (dxy.y + EPS);
        float rx2 = 1.0f / (dxy.x * dxy.x + EPS);
        float ry2 = 1.0f / (dxy.y * dxy.y + EPS);
        float du_dx = du * rx, du_dy = du * ry;
        float dv_dx = dv * rx, dv_dy = dv * ry;
        float nu_eff = NU_MOL + pr.w;
        atomicAdd(&a_cnt[row], 1.0f);
        atomicAdd(&a_div[row], du_dx + dv_dy);
        atomicAdd(&a_mx[row], dp * rx + nu_eff * du * rx2);
        atomicAdd(&a_my[row], dp * ry + nu_eff * dv * ry2);
        float sh = du_dy + dv_dx;
        atomicAdd(&a_str[row], 2.0f * (du_dx * du_dx + dv_dy * dv_dy) + sh * sh);
        smooth += (double)(du * du + dv * dv + dp * dp + dn * dn);
    }
    for (int off = 32; off > 0; off >>= 1)
        smooth += __shfl_down(smooth, off);
    __shared__ double sm[4];
    int lane = threadIdx.x & 63, wv = threadIdx.x >> 6;
    if (lane == 0) sm[wv] = smooth;
    __syncthreads();
    if (threadIdx.x == 0)
        atomicAdd(&smooth_slots[blockIdx.x & 63], sm[0] + sm[1] + sm[2] + sm[3]);
}

__global__ __launch_bounds__(256) void node_kernel(
    const float4* __restrict__ pred, const float4* __restrict__ tgt,
    const unsigned char* __restrict__ wall, int N,
    const float* __restrict__ a_cnt, const float* __restrict__ a_div,
    const float* __restrict__ a_mx, const float* __restrict__ a_my,
    const float* __restrict__ a_str, double* __restrict__ d)
{
    int i = blockIdx.x * blockDim.x + threadIdx.x;
    double v0 = 0, v1 = 0, v2 = 0, v3 = 0, v4 = 0, v5 = 0, v6 = 0, v7 = 0;
    if (i < N) {
        float4 p = pred[i];
        float4 t = tgt[i];
        float inv = 1.0f / fmaxf(a_cnt[i], 1.0f);
        float div = a_div[i] * inv;
        float mx = a_mx[i] * inv, my = a_my[i] * inv;
        float sn = a_str[i] * inv;
        float prod = p.w * sn;
        float m = wall[i] ? 1.0f : 0.0f;
        float e0 = p.x - t.x, e1 = p.y - t.y, e2 = p.z - t.z, e3 = p.w - t.w;
        float uv = p.x * p.x + p.y * p.y;
        v0 = (double)(e0 * e0 + e1 * e1 + e2 * e2 + e3 * e3);
        v1 = (double)div * (double)div;
        v2 = (double)mx * (double)mx + (double)my * (double)my;
        v3 = (double)prod * (double)prod;
        v4 = (double)p.w * (double)p.w;
        v5 = (double)m;
        v6 = (double)(m * uv);
        v7 = (double)(m * (uv + p.w * p.w));
    }
    for (int off = 32; off > 0; off >>= 1) {
        v0 += __shfl_down(v0, off); v1 += __shfl_down(v1, off);
        v2 += __shfl_down(v2, off); v3 += __shfl_down(v3, off);
        v4 += __shfl_down(v4, off); v5 += __shfl_down(v5, off);
        v6 += __shfl_down(v6, off); v7 += __shfl_down(v7, off);
    }
    __shared__ double sm[4][8];
    int lane = threadIdx.x & 63, wv = threadIdx.x >> 6;
    if (lane == 0) {
        sm[wv][0] = v0; sm[wv][1] = v1; sm[wv][2] = v2; sm[wv][3] = v3;
        sm[wv][4] = v4; sm[wv][5] = v5; sm[wv][6] = v6; sm[wv][7] = v7;
    }
    __syncthreads();
    if (threadIdx.x < 8) {
        int q = threadIdx.x;
        atomicAdd(&d[q], sm[0][q] + sm[1][q] + sm[2][q] + sm[3][q]);
    }
}

// ===================== launch =====================

extern "C" void kernel_launch(void* const* d_in, const int* in_sizes, int n_in,
                              void* d_out, int out_size, void* d_ws, size_t ws_size,
                              hipStream_t stream) {
    const float4* pred = (const float4*)d_in[0];
    const float4* tgt  = (const float4*)d_in[1];
    const float2* eattr = (const float2*)d_in[2];
    const void* eidx = d_in[3];
    const unsigned char* wall = (const unsigned char*)d_in[4];
    int N = in_sizes[0] / 4;
    int E = in_sizes[2] / 2;
    int NB = (N + NPB - 1) / NPB;
    int chunk = (E + NBLK - 1) / NBLK;
    int ntiles = (NB + 63) / 64;

    char* ws = (char*)d_ws;
    double* d = (double*)ws;                 // 8 scalars
    double* smooth_slots = d + 8;            // 64 slots
    int* flag = (int*)(ws + 576);

    size_t off = 1024;
    unsigned* counts = (unsigned*)(ws + off); off += (size_t)NBLK * NBP * 4;
    unsigned* gsum   = (unsigned*)(ws + off); off += (size_t)NGRP * NBP * 4;
    unsigned* base   = (unsigned*)(ws + off); off += (size_t)(NB + 1) * 4;
    off = (off + 15) & ~(size_t)15;
    uint2* vals      = (uint2*)(ws + off);    off += (size_t)E * 8;
    unsigned char* rl8 = (unsigned char*)(ws + off); off += (size_t)E;
    size_t need_fast = off;

    bool fast = (NB <= MAXNB) && (chunk <= CMAX) && (ws_size >= need_fast);

    if (fast) {
        hipMemsetAsync(d_ws, 0, 1024, stream);
        detect_idx_dtype<<<1, 1, 0, stream>>>(eidx, N, flag);
        count_kernel<<<NBLK, 256, 0, stream>>>(eidx, E, N, NB, flag, counts);
        group_sums_kernel<<<dim3(NGRP, ntiles), 256, 0, stream>>>(counts, gsum, NB);
        scan_base_kernel<<<1, 512, 0, stream>>>(gsum, base, NB);
        local_scan_kernel<<<dim3(NGRP, ntiles), 256, 0, stream>>>(counts, gsum, NB);
        sort_scatter_kernel<<<NBLK, 256, 0, stream>>>(eidx, eattr, pred, E, N, NB,
                                                      flag, counts, vals, rl8,
                                                      smooth_slots);
        bucket_kernel<<<NB, 256, 0, stream>>>(vals, rl8, base, pred, tgt, wall, N, d);
        finalize_kernel<<<1, 1, 0, stream>>>(d, smooth_slots, N, E, (float*)d_out);
    } else {
        float* arrays = (float*)(ws + 1024);
        float* a_cnt = arrays + (size_t)0 * N;
        float* a_div = arrays + (size_t)1 * N;
        float* a_mx  = arrays + (size_t)2 * N;
        float* a_my  = arrays + (size_t)3 * N;
        float* a_str = arrays + (size_t)4 * N;
        size_t zbytes = 1024 + (size_t)5 * N * sizeof(float);
        hipMemsetAsync(d_ws, 0, zbytes, stream);
        detect_idx_dtype<<<1, 1, 0, stream>>>(eidx, N, flag);
        edge_kernel<<<4096, 256, 0, stream>>>(eidx, eattr, pred, E, N, flag,
                                              a_cnt, a_div, a_mx, a_my, a_str,
                                              smooth_slots);
        node_kernel<<<(N + 255) / 256, 256, 0, stream>>>(pred, tgt, wall, N,
                                                         a_cnt, a_div, a_mx, a_my,
                                                         a_str, d);
        finalize_kernel<<<1, 1, 0, stream>>>(d, smooth_slots, N, E, (float*)d_out);
    }
}